// Round 9
// baseline (1455.190 us; speedup 1.0000x reference)
//
#include <hip/hip_runtime.h>
#include <hip/hip_bf16.h>
#include <math.h>

#define B_    128
#define L_    128
#define DIN   6
#define D_    256
#define H_    8
#define NL_   6
#define NE_   8
#define DFF_  1024
#define NOUT_ 5
#define T_    (B_*L_)      /* 16384 tokens */
#define DK_   32
#define NDESC_MAX 264      /* 32768/128 + 8 experts ceil slack */

typedef unsigned short u16;
typedef __hip_bfloat16 bf16;
typedef __attribute__((ext_vector_type(8))) short short8;
typedef __attribute__((ext_vector_type(8))) unsigned short ushort8v;
typedef __attribute__((ext_vector_type(4))) unsigned short ushort4v;
typedef __attribute__((ext_vector_type(4))) float floatx4;

// small f32 canon region: x, emb_w, emb_b, wfreq, wphase, rtw, rtb, eb1,
// eb2, ln_g, ln_b, pred_w, pred_b, unc_w, unc_b
__device__ const int S_PRE[16] = {
    0, 98304, 99840, 100096, 100144, 100192, 106336, 106360,
    130936, 137080, 137336, 137592, 138872, 138877, 140157, 140162};
__device__ const int S_SRC[15] = {0,1,2,7,8,9,10,12,14,15,16,17,18,19,20};
#define NSMALL 140162

struct SrcPtrs { const void* p[21]; };

__device__ __forceinline__ float bf2f(u16 u) {
    return __uint_as_float(((unsigned)u) << 16);
}
__device__ __forceinline__ u16 f2bf(float f) {
    union { bf16 b; u16 u; } c; c.b = __float2bfloat16(f); return c.u;
}
__device__ __forceinline__ float gelu_f(float x) {
    return 0.5f * x * (1.0f + erff(x * 0.70710678118654752f));
}

// ---------------------------------------------------------------------------
// Canonicalize small tensors to f32 (dtype probe: ln_g[0]==0x3F80 iff bf16)
// ---------------------------------------------------------------------------
__global__ __launch_bounds__(256)
void conv_small_kernel(SrcPtrs P, float* __restrict__ dst)
{
    const int i = blockIdx.x * 256 + threadIdx.x;
    if (i >= NSMALL) return;
    int seg = 0;
    #pragma unroll
    for (int s = 1; s < 15; ++s) seg += (i >= S_PRE[s]) ? 1 : 0;
    const int off = i - S_PRE[seg];
    const void* src = P.p[S_SRC[seg]];
    const bool isbf = (((const u16*)P.p[15])[0] == 0x3F80);
    if (isbf) dst[i] = bf2f(((const u16*)src)[off]);
    else      dst[i] = ((const float*)src)[off];
}

// ---------------------------------------------------------------------------
// TILED weight transpose+cast: dst[z][(n+noff)][k] = src[z][k][n], 64x64 tiles
// via LDS (R8-verified, -30us vs scattered). grid: (z, KD/64, ND/64), 256 thr.
// ---------------------------------------------------------------------------
template<int KD, int ND>
__global__ __launch_bounds__(256)
void transpose_tiled(const void* __restrict__ src, const u16* __restrict__ probe,
                     u16* __restrict__ dst, long dzs, int noff)
{
    const int z  = blockIdx.x;
    const int k0 = blockIdx.y * 64;
    const int n0 = blockIdx.z * 64;
    __shared__ u16 tile[64][66];     // row len 66: <=4-way on column gather
    const int tid = threadIdx.x;
    const bool isbf = (probe[0] == 0x3F80);

    if (isbf) {
        const u16* s = (const u16*)src + (size_t)z * KD * ND + (size_t)k0 * ND + n0;
        #pragma unroll
        for (int p = 0; p < 2; ++p) {
            const int c  = p * 256 + tid;
            const int kk = c >> 3, nn = (c & 7) * 8;
            *(ushort8v*)&tile[kk][nn] = *(const ushort8v*)(s + (size_t)kk * ND + nn);
        }
    } else {
        const float* s = (const float*)src + (size_t)z * KD * ND + (size_t)k0 * ND + n0;
        #pragma unroll
        for (int p = 0; p < 2; ++p) {
            const int c  = p * 256 + tid;
            const int kk = c >> 3, nn = (c & 7) * 8;
            float4 v0 = *(const float4*)(s + (size_t)kk * ND + nn);
            float4 v1 = *(const float4*)(s + (size_t)kk * ND + nn + 4);
            ushort8v t;
            t[0]=f2bf(v0.x); t[1]=f2bf(v0.y); t[2]=f2bf(v0.z); t[3]=f2bf(v0.w);
            t[4]=f2bf(v1.x); t[5]=f2bf(v1.y); t[6]=f2bf(v1.z); t[7]=f2bf(v1.w);
            *(ushort8v*)&tile[kk][nn] = t;
        }
    }
    __syncthreads();

    u16* d = dst + (size_t)z * dzs + (size_t)(n0 + noff) * KD + k0;
    #pragma unroll
    for (int p = 0; p < 2; ++p) {
        const int c  = p * 256 + tid;
        const int nn = c >> 3, kk = (c & 7) * 8;
        ushort8v t;
        #pragma unroll
        for (int j = 0; j < 8; ++j) t[j] = tile[kk + j][nn];
        *(ushort8v*)&d[(size_t)nn * KD + kk] = t;
    }
}

// ---------------------------------------------------------------------------
// Embedding (all f32) + bf16 mirror
// ---------------------------------------------------------------------------
__global__ __launch_bounds__(256)
void embed_kernel(const float* __restrict__ x, const float* __restrict__ emb_w,
                  const float* __restrict__ emb_b, float* __restrict__ h,
                  u16* __restrict__ hb)
{
    const int idx = blockIdx.x * 256 + threadIdx.x;
    const int t = idx >> 8;
    const int d = idx & 255;
    float acc = emb_b[d];
    #pragma unroll
    for (int j = 0; j < DIN; ++j)
        acc += x[t * DIN + j] * emb_w[j * D_ + d];
    h[idx]  = acc;
    hb[idx] = f2bf(acc);
}

// ---------------------------------------------------------------------------
// DIRECT-TO-REGISTER MFMA GEMM: NO LDS, NO BARRIERS.
// Rationale (R2-R8): five LDS+barrier schedules all plateau at 200-260 TF,
// MfmaUtil <=10%, ~97% idle cycles — the barrier-coupled per-K-step stage
// convoys all waves on the slowest load. Operands are L2/L3-resident at this
// problem size, so each wave loads its MFMA fragments straight from global:
//   A-frag af[i]: 64 lanes read rows wm*64+(lane&15)+16i, 16B at col fk
//   B-frag bf[j]: same pattern on W^T panel
// 8 base pointers/lane computed once; K walked by immediate offsets.
// Pure dataflow K-loop -> compiler pipelines loads freely, waves independent.
// Tile 128x128, 4 waves (wm=wave&1, wn=wave>>1), acc[4][4] = 64 VGPR.
// MODE 0: dense rows (Mfixed)   MODE 1: per-lane gather via atok (MoE w1)
// MODE 2: slot rows (sbase+rr)  (MoE w2)
// EPI 0: bf16 C (QKV)  EPI 1: f32 += & bf16 mirror (o-proj)
// EPI 2: +bias,gelu->bf16 (w1)  EPI 3: +bias->f32 (w2)
// ---------------------------------------------------------------------------
template<int EPI, int MODE, int NT>
__global__ __launch_bounds__(256)
void mfma_gemm(const u16* __restrict__ A, int lda,
               const u16* __restrict__ Wt, long wzs, int ldwt,
               const float* __restrict__ biasb, long bzs,
               void* __restrict__ CoutV, int ldc,
               u16* __restrict__ hbout, int Mfixed,
               const int* __restrict__ cnt, const int* __restrict__ base_,
               const int* __restrict__ atok,
               const int* __restrict__ de, const int* __restrict__ dr,
               const int* __restrict__ ndesc)
{
    int M, r0, sbase = 0, e = 0;
    if constexpr (MODE == 0) {
        M  = Mfixed;
        r0 = blockIdx.x * 128;
        if (r0 >= M) return;
    } else {
        const int i = blockIdx.x;
        if (i >= *ndesc) return;
        e     = de[i];
        r0    = dr[i] * 128;
        sbase = base_[e];
        M     = cnt[e];
    }
    const u16*   W    = Wt + (size_t)e * wzs;
    const float* bias = biasb ? (biasb + (size_t)e * bzs) : nullptr;
    const int col0 = blockIdx.y * 128;

    const int tid  = threadIdx.x;
    const int lane = tid & 63;
    const int wave = tid >> 6;
    const int wm = wave & 1, wn = wave >> 1;

    const int fm = wm * 64 + (lane & 15);           // frag base row
    const int fn = wn * 64 + (lane & 15);           // frag base col
    const int fk = (lane >> 4) * 8;                 // k sub-offset (u16)

    // per-lane fragment base pointers (computed once; K via imm offsets)
    const u16* pa[4];
    const u16* pb[4];
    #pragma unroll
    for (int i = 0; i < 4; ++i) {
        int rr = r0 + fm + 16 * i;
        if (rr >= M) rr = M - 1;
        long arow;
        if constexpr (MODE == 1)      arow = atok[sbase + rr];
        else if constexpr (MODE == 2) arow = (long)(sbase + rr);
        else                          arow = (long)rr;
        pa[i] = A + arow * (long)lda + fk;
    }
    #pragma unroll
    for (int j = 0; j < 4; ++j)
        pb[j] = W + (size_t)(col0 + fn + 16 * j) * ldwt + fk;

    floatx4 acc[4][4];
    #pragma unroll
    for (int i = 0; i < 4; ++i)
        #pragma unroll
        for (int j = 0; j < 4; ++j)
            acc[i][j] = (floatx4){0.f, 0.f, 0.f, 0.f};

    #pragma unroll 4
    for (int t = 0; t < NT; ++t) {
        const int ko = t * 32;
        short8 af[4], bfr[4];
        #pragma unroll
        for (int i = 0; i < 4; ++i) af[i]  = *(const short8*)(pa[i] + ko);
        #pragma unroll
        for (int j = 0; j < 4; ++j) bfr[j] = *(const short8*)(pb[j] + ko);
        #pragma unroll
        for (int i = 0; i < 4; ++i)
            #pragma unroll
            for (int j = 0; j < 4; ++j)
                acc[i][j] = __builtin_amdgcn_mfma_f32_16x16x32_bf16(
                    af[i], bfr[j], acc[i][j], 0, 0, 0);
    }

    const int er = wm * 64 + ((lane >> 4) << 2);
    const int ec = wn * 64 + (lane & 15);
    #pragma unroll
    for (int i = 0; i < 4; ++i) {
        #pragma unroll
        for (int reg = 0; reg < 4; ++reg) {
            const int lrow = r0 + er + i * 16 + reg;
            if (lrow >= M) continue;
            const long crow = (MODE == 0) ? (long)lrow : (long)(sbase + lrow);
            #pragma unroll
            for (int j = 0; j < 4; ++j) {
                const int cj = col0 + ec + j * 16;
                const float val = acc[i][j][reg];
                if constexpr (EPI == 0) {
                    ((u16*)CoutV)[crow * ldc + cj] = f2bf(val);
                } else if constexpr (EPI == 1) {
                    const size_t idx = crow * ldc + cj;
                    const float nv = ((float*)CoutV)[idx] + val;
                    ((float*)CoutV)[idx] = nv;
                    hbout[idx] = f2bf(nv);
                } else if constexpr (EPI == 2) {
                    ((u16*)CoutV)[crow * ldc + cj] = f2bf(gelu_f(val + bias[cj]));
                } else {
                    ((float*)CoutV)[crow * ldc + cj] = val + bias[cj];
                }
            }
        }
    }
}

// ---------------------------------------------------------------------------
// MFMA wave attention, one block (256 thr, 4 waves) per (b, head).
// ---------------------------------------------------------------------------
__global__ __launch_bounds__(256)
void attn_kernel(const u16* __restrict__ qkv, u16* __restrict__ o,
                 const float* __restrict__ wfreq, const float* __restrict__ wphase)
{
    const int bh = blockIdx.x;
    const int b  = bh >> 3;
    const int hh = bh & 7;

    __shared__ __attribute__((aligned(16))) u16 Qs[128][40];
    __shared__ __attribute__((aligned(16))) u16 Ks[128][40];
    __shared__ __attribute__((aligned(16))) u16 Vt[32][136];
    __shared__ __attribute__((aligned(16))) u16 Ps[128][136];
    __shared__ float wavec[128];

    const int tid  = threadIdx.x;
    const int lane = tid & 63;
    const int w    = tid >> 6;
    const int col16 = lane & 15;
    const int quad  = lane >> 4;

    const long qbase = (long)b * L_ * 768 + hh * DK_;

    // stage Q, K, V^T (bf16)
    {
        const int row = tid >> 1;
        const int hf  = (tid & 1) * 16;
        const u16* src = qkv + qbase + (long)row * 768 + hf;
        *(ushort8v*)&Qs[row][hf]     = *(const ushort8v*)(src);
        *(ushort8v*)&Qs[row][hf + 8] = *(const ushort8v*)(src + 8);
        *(ushort8v*)&Ks[row][hf]     = *(const ushort8v*)(src + 256);
        *(ushort8v*)&Ks[row][hf + 8] = *(const ushort8v*)(src + 264);
        #pragma unroll
        for (int j = 0; j < 16; ++j)
            Vt[hf + j][row] = src[512 + j];
    }
    if (tid < L_) {
        float f2 = 6.2831853071795864769f * wfreq[hh];
        wavec[tid] = cosf(f2 * (float)tid + wphase[hh]);
    }
    __syncthreads();

    const float scale = 0.17677669529663687f;   // 1/sqrt(32)
    float wv8[8];
    #pragma unroll
    for (int ni = 0; ni < 8; ++ni)
        wv8[ni] = scale * wavec[ni * 16 + col16];

    // S = Q K^T : wave w owns rows [w*32, w*32+32)
    const int m0 = w * 32;
    floatx4 accs[2][8];
    {
        short8 a0 = *(const short8*)&Qs[m0 + col16][quad * 8];
        short8 a1 = *(const short8*)&Qs[m0 + 16 + col16][quad * 8];
        #pragma unroll
        for (int ni = 0; ni < 8; ++ni) {
            short8 bf = *(const short8*)&Ks[ni * 16 + col16][quad * 8];
            accs[0][ni] = __builtin_amdgcn_mfma_f32_16x16x32_bf16(
                a0, bf, (floatx4){0.f,0.f,0.f,0.f}, 0, 0, 0);
            accs[1][ni] = __builtin_amdgcn_mfma_f32_16x16x32_bf16(
                a1, bf, (floatx4){0.f,0.f,0.f,0.f}, 0, 0, 0);
        }
    }
    #pragma unroll
    for (int mi = 0; mi < 2; ++mi)
        #pragma unroll
        for (int ni = 0; ni < 8; ++ni)
            #pragma unroll
            for (int reg = 0; reg < 4; ++reg)
                accs[mi][ni][reg] *= wv8[ni];

    // full-row softmax: row = m0 + mi*16 + quad*4 + reg, in-wave
    #pragma unroll
    for (int mi = 0; mi < 2; ++mi) {
        #pragma unroll
        for (int reg = 0; reg < 4; ++reg) {
            float rmax = -1e30f;
            #pragma unroll
            for (int ni = 0; ni < 8; ++ni)
                rmax = fmaxf(rmax, accs[mi][ni][reg]);
            #pragma unroll
            for (int off = 1; off < 16; off <<= 1)
                rmax = fmaxf(rmax, __shfl_xor(rmax, off));
            float e[8], rsum = 0.0f;
            #pragma unroll
            for (int ni = 0; ni < 8; ++ni) {
                e[ni] = expf(accs[mi][ni][reg] - rmax);
                rsum += e[ni];
            }
            #pragma unroll
            for (int off = 1; off < 16; off <<= 1)
                rsum += __shfl_xor(rsum, off);
            const float inv = 1.0f / rsum;
            const int row = m0 + mi * 16 + quad * 4 + reg;
            #pragma unroll
            for (int ni = 0; ni < 8; ++ni)
                Ps[row][ni * 16 + col16] = f2bf(e[ni] * inv);
        }
    }
    __syncthreads();

    // O = P V
    floatx4 acco[2][2];
    #pragma unroll
    for (int mi = 0; mi < 2; ++mi)
        #pragma unroll
        for (int nj = 0; nj < 2; ++nj)
            acco[mi][nj] = (floatx4){0.f,0.f,0.f,0.f};
    #pragma unroll
    for (int kk = 0; kk < 4; ++kk) {
        short8 a0 = *(const short8*)&Ps[m0 + col16][kk * 32 + quad * 8];
        short8 a1 = *(const short8*)&Ps[m0 + 16 + col16][kk * 32 + quad * 8];
        short8 b0 = *(const short8*)&Vt[col16][kk * 32 + quad * 8];
        short8 b1 = *(const short8*)&Vt[16 + col16][kk * 32 + quad * 8];
        acco[0][0] = __builtin_amdgcn_mfma_f32_16x16x32_bf16(a0, b0, acco[0][0], 0, 0, 0);
        acco[0][1] = __builtin_amdgcn_mfma_f32_16x16x32_bf16(a0, b1, acco[0][1], 0, 0, 0);
        acco[1][0] = __builtin_amdgcn_mfma_f32_16x16x32_bf16(a1, b0, acco[1][0], 0, 0, 0);
        acco[1][1] = __builtin_amdgcn_mfma_f32_16x16x32_bf16(a1, b1, acco[1][1], 0, 0, 0);
    }

    const long obase = (long)b * L_ * D_ + hh * DK_;
    #pragma unroll
    for (int mi = 0; mi < 2; ++mi)
        #pragma unroll
        for (int reg = 0; reg < 4; ++reg) {
            const int row = m0 + mi * 16 + quad * 4 + reg;
            #pragma unroll
            for (int nj = 0; nj < 2; ++nj)
                o[obase + (long)row * D_ + nj * 16 + col16] =
                    f2bf(acco[mi][nj][reg]);
        }
}

// ---------------------------------------------------------------------------
// MoE router: one WAVE per token.
// ---------------------------------------------------------------------------
__global__ __launch_bounds__(256)
void router_kernel(const float* __restrict__ h, const float* __restrict__ rtw,
                   const float* __restrict__ rtb, int* __restrict__ te,
                   float* __restrict__ twt)
{
    const int tid  = threadIdx.x;
    const int lane = tid & 63;
    const int wv   = tid >> 6;
    const int t    = blockIdx.x * 4 + wv;

    const float4 hv = ((const float4*)(h + (long)t * D_))[lane];
    const float4* rp = (const float4*)rtw;

    float lg[NE_];
    #pragma unroll
    for (int e = 0; e < NE_; ++e) lg[e] = 0.0f;
    #pragma unroll
    for (int i = 0; i < 4; ++i) {
        const int d = lane * 4 + i;
        const float xv = (i == 0) ? hv.x : (i == 1) ? hv.y : (i == 2) ? hv.z : hv.w;
        float4 wa = rp[d * 2 + 0];
        float4 wb = rp[d * 2 + 1];
        lg[0] = fmaf(xv, wa.x, lg[0]);
        lg[1] = fmaf(xv, wa.y, lg[1]);
        lg[2] = fmaf(xv, wa.z, lg[2]);
        lg[3] = fmaf(xv, wa.w, lg[3]);
        lg[4] = fmaf(xv, wb.x, lg[4]);
        lg[5] = fmaf(xv, wb.y, lg[5]);
        lg[6] = fmaf(xv, wb.z, lg[6]);
        lg[7] = fmaf(xv, wb.w, lg[7]);
    }
    #pragma unroll
    for (int off = 1; off < 64; off <<= 1)
        #pragma unroll
        for (int e = 0; e < NE_; ++e)
            lg[e] += __shfl_xor(lg[e], off);

    if (lane == 0) {
        #pragma unroll
        for (int e = 0; e < NE_; ++e) lg[e] += rtb[e];
        int i1 = 0; float v1 = lg[0];
        #pragma unroll
        for (int e = 1; e < NE_; ++e) { if (lg[e] > v1) { v1 = lg[e]; i1 = e; } }
        int i2 = (i1 == 0) ? 1 : 0; float v2 = lg[i2];
        #pragma unroll
        for (int e = 0; e < NE_; ++e) {
            if (e != i1 && lg[e] > v2) { v2 = lg[e]; i2 = e; }
        }
        float r   = expf(v2 - v1);
        float wa1 = 1.0f / (1.0f + r);
        te[2 * t]     = i1;
        te[2 * t + 1] = i2;
        twt[2 * t]     = wa1;
        twt[2 * t + 1] = r * wa1;
    }
}

// ---------------------------------------------------------------------------
// Count experts + exclusive scan + zero cursors + tile descriptors (128-row).
// ---------------------------------------------------------------------------
__global__ __launch_bounds__(512)
void countscan_kernel(const int* __restrict__ te, int* __restrict__ cnt,
                      int* __restrict__ base_, int* __restrict__ cursor,
                      int* __restrict__ de, int* __restrict__ dr,
                      int* __restrict__ ndesc)
{
    const int tid = threadIdx.x;
    int c[NE_];
    #pragma unroll
    for (int e = 0; e < NE_; ++e) c[e] = 0;
    for (int i = tid; i < 2 * T_; i += 512) {
        const int e = te[i];
        #pragma unroll
        for (int ee = 0; ee < NE_; ++ee) c[ee] += (e == ee) ? 1 : 0;
    }
    #pragma unroll
    for (int off = 1; off < 64; off <<= 1)
        #pragma unroll
        for (int e = 0; e < NE_; ++e)
            c[e] += __shfl_xor(c[e], off);

    __shared__ int wsum[8][NE_];
    const int lane = tid & 63, wv = tid >> 6;
    if (lane == 0)
        #pragma unroll
        for (int e = 0; e < NE_; ++e) wsum[wv][e] = c[e];
    __syncthreads();
    if (tid == 0) {
        int a = 0, n = 0;
        for (int e = 0; e < NE_; ++e) {
            int s = 0;
            for (int w = 0; w < 8; ++w) s += wsum[w][e];
            cnt[e] = s;
            base_[e] = a;
            a += s;
            const int nb = (s + 127) >> 7;
            for (int rb = 0; rb < nb; ++rb) {
                de[n] = e; dr[n] = rb; ++n;
            }
        }
        *ndesc = n;
    }
    if (tid < NE_) cursor[tid] = 0;
}

// ---------------------------------------------------------------------------
// Scatter with LDS rank aggregation: 8 global atomics per block.
// ---------------------------------------------------------------------------
__global__ __launch_bounds__(256)
void scatter_kernel(const int* __restrict__ te, const int* __restrict__ base_,
                    int* __restrict__ cursor, int* __restrict__ atok,
                    int* __restrict__ tslot)
{
    __shared__ int lcnt[NE_];
    __shared__ int gb[NE_];
    const int tid = threadIdx.x;
    if (tid < NE_) lcnt[tid] = 0;
    __syncthreads();

    const int i0 = blockIdx.x * 512 + tid * 2;
    const int e0 = te[i0], e1 = te[i0 + 1];
    const int r0 = atomicAdd(&lcnt[e0], 1);
    const int r1 = atomicAdd(&lcnt[e1], 1);
    __syncthreads();
    if (tid < NE_) gb[tid] = atomicAdd(&cursor[tid], lcnt[tid]);
    __syncthreads();

    const int s0 = base_[e0] + gb[e0] + r0;
    const int s1 = base_[e1] + gb[e1] + r1;
    atok[s0] = i0 >> 1;
    atok[s1] = i0 >> 1;
    tslot[i0]     = s0;
    tslot[i0 + 1] = s1;
}

// ---------------------------------------------------------------------------
// Combine, vectorized: f32x4 per thread (R8-verified).
// ---------------------------------------------------------------------------
__global__ __launch_bounds__(256)
void combine_kernel(float* __restrict__ h, u16* __restrict__ hb,
                    const float* __restrict__ eo,
                    const float* __restrict__ twt, const int* __restrict__ tslot)
{
    const int i = blockIdx.x * 256 + threadIdx.x;
    const int t = i >> 6;                 // token
    const int g = i & 63;                 // f32x4 group within row (D/4=64)
    const int s0 = tslot[2 * t], s1 = tslot[2 * t + 1];
    const float w0 = twt[2 * t], w1 = twt[2 * t + 1];
    float4 a  = ((const float4*)(eo + (size_t)s0 * D_))[g];
    float4 b  = ((const float4*)(eo + (size_t)s1 * D_))[g];
    float4 hv = ((const float4*)(h + (size_t)t * D_))[g];
    hv.x += w0 * a.x + w1 * b.x;
    hv.y += w0 * a.y + w1 * b.y;
    hv.z += w0 * a.z + w1 * b.z;
    hv.w += w0 * a.w + w1 * b.w;
    ((float4*)(h + (size_t)t * D_))[g] = hv;
    ushort4v pk;
    pk[0] = f2bf(hv.x); pk[1] = f2bf(hv.y); pk[2] = f2bf(hv.z); pk[3] = f2bf(hv.w);
    *(ushort4v*)&hb[(size_t)t * D_ + g * 4] = pk;
}

// ---------------------------------------------------------------------------
// Final: LN on last-position tokens, pred / softplus heads. f32 output.
// ---------------------------------------------------------------------------
__global__ __launch_bounds__(256)
void final_kernel(const float* __restrict__ h, const float* __restrict__ ln_g,
                  const float* __restrict__ ln_b, const float* __restrict__ pred_w,
                  const float* __restrict__ pred_b, const float* __restrict__ unc_w,
                  const float* __restrict__ unc_b, float* __restrict__ out)
{
    const int b = blockIdx.x;
    const int d = threadIdx.x;
    const long t = (long)b * L_ + (L_ - 1);
    const float val = h[t * D_ + d];

    __shared__ float red[4];
    __shared__ float lat[D_];

    float s = val;
    #pragma unroll
    for (int off = 32; off > 0; off >>= 1) s += __shfl_down(s, off);
    if ((d & 63) == 0) red[d >> 6] = s;
    __syncthreads();
    const float mean = (red[0] + red[1] + red[2] + red[3]) * (1.0f / D_);
    __syncthreads();

    const float dv = val - mean;
    s = dv * dv;
    #pragma unroll
    for (int off = 32; off > 0; off >>= 1) s += __shfl_down(s, off);
    if ((d & 63) == 0) red[d >> 6] = s;
    __syncthreads();
    const float var = (red[0] + red[1] + red[2] + red[3]) * (1.0f / D_);

    lat[d] = dv * rsqrtf(var + 1e-5f) * ln_g[d] + ln_b[d];
    __syncthreads();

    if (d < 2 * NOUT_) {
        const int j = d % NOUT_;
        const int sel = d / NOUT_;
        const float* w  = sel ? unc_w : pred_w;
        const float* bb = sel ? unc_b : pred_b;
        float acc = bb[j];
        for (int dd = 0; dd < D_; ++dd)
            acc = fmaf(lat[dd], w[dd * NOUT_ + j], acc);
        if (sel) acc = log1pf(expf(acc));
        out[sel * (B_ * NOUT_) + b * NOUT_ + j] = acc;
    }
}

// ---------------------------------------------------------------------------
extern "C" void kernel_launch(void* const* d_in, const int* in_sizes, int n_in,
                              void* d_out, int out_size, void* d_ws, size_t ws_size,
                              hipStream_t stream)
{
    (void)in_sizes; (void)n_in; (void)out_size; (void)ws_size;

    char* ws = (char*)d_ws;
    size_t off = 0;
    auto alloc = [&](size_t bytes) {
        size_t cur = off;
        off += (bytes + 255) & ~(size_t)255;
        return (void*)(ws + cur);
    };
    float* cs     = (float*)alloc((size_t)NSMALL * 4);
    u16*   qkvt   = (u16*)  alloc((size_t)NL_ * 768 * 256 * 2);
    u16*   wot    = (u16*)  alloc((size_t)NL_ * 256 * 256 * 2);
    u16*   ew1t   = (u16*)  alloc((size_t)3 * NE_ * DFF_ * D_ * 2);
    u16*   ew2t   = (u16*)  alloc((size_t)3 * NE_ * D_ * DFF_ * 2);
    float* h      = (float*)alloc((size_t)T_ * D_ * 4);
    u16*   hb     = (u16*)  alloc((size_t)T_ * D_ * 2);
    // union region: attn-phase {qkvb, ob} aliases moe-phase {hidden, eo}
    char*  uni    = (char*) alloc((size_t)2 * T_ * DFF_ * 2 + (size_t)2 * T_ * D_ * 4);
    u16*   qkvb   = (u16*)  uni;                                    // 25.2 MB
    u16*   ob     = (u16*)  (uni + (size_t)T_ * 768 * 2 + 256);     //  8.4 MB
    u16*   hidden = (u16*)  uni;                                    // 67.1 MB
    float* eo     = (float*)(uni + (size_t)2 * T_ * DFF_ * 2);      // 33.6 MB
    int*   te     = (int*)  alloc((size_t)2 * T_ * 4);
    float* twt    = (float*)alloc((size_t)2 * T_ * 4);
    int*   atok   = (int*)  alloc((size_t)2 * T_ * 4);
    int*   tslot  = (int*)  alloc((size_t)2 * T_ * 4);
    int*   cnt    = (int*)  alloc(64 * 4);
    int*   base_  = (int*)  alloc(64 * 4);
    int*   cursor = (int*)  alloc(64 * 4);
    int*   de     = (int*)  alloc(NDESC_MAX * 4);
    int*   dr     = (int*)  alloc(NDESC_MAX * 4);
    int*   ndesc  = (int*)  alloc(64 * 4);

    SrcPtrs P;
    for (int i = 0; i < 21; ++i) P.p[i] = d_in[i];
    const u16* probe = (const u16*)d_in[15];

    conv_small_kernel<<<(NSMALL + 255) / 256, 256, 0, stream>>>(P, cs);
    transpose_tiled<256,256><<<dim3(NL_, 4, 4), 256, 0, stream>>>(
        d_in[3], probe, qkvt, 768L * 256, 0);
    transpose_tiled<256,256><<<dim3(NL_, 4, 4), 256, 0, stream>>>(
        d_in[4], probe, qkvt, 768L * 256, 256);
    transpose_tiled<256,256><<<dim3(NL_, 4, 4), 256, 0, stream>>>(
        d_in[5], probe, qkvt, 768L * 256, 512);
    transpose_tiled<256,256><<<dim3(NL_, 4, 4), 256, 0, stream>>>(
        d_in[6], probe, wot, 65536L, 0);
    transpose_tiled<256,1024><<<dim3(24, 4, 16), 256, 0, stream>>>(
        d_in[11], probe, ew1t, 262144L, 0);
    transpose_tiled<1024,256><<<dim3(24, 16, 4), 256, 0, stream>>>(
        d_in[13], probe, ew2t, 262144L, 0);

    const float* x      = cs;
    const float* emb_w  = cs + 98304;
    const float* emb_b  = cs + 99840;
    const float* wfreq  = cs + 100096;
    const float* wphase = cs + 100144;
    const float* rtw    = cs + 100192;
    const float* rtb    = cs + 106336;
    const float* eb1    = cs + 106360;
    const float* eb2    = cs + 130936;
    const float* ln_g   = cs + 137080;
    const float* ln_b   = cs + 137336;
    const float* pred_w = cs + 137592;
    const float* pred_b = cs + 138872;
    const float* unc_w  = cs + 138877;
    const float* unc_b  = cs + 140157;

    embed_kernel<<<(T_ * D_) / 256, 256, 0, stream>>>(x, emb_w, emb_b, h, hb);

    for (int i = 0; i < NL_; ++i) {
        // QKV: [16384 x 768] = hb[16384 x 256] @ qkvt^T
        mfma_gemm<0, 0, 8><<<dim3(T_/128, 6, 1), 256, 0, stream>>>(
            hb, D_, qkvt + (size_t)i * 768 * 256, 0, 256,
            nullptr, 0, qkvb, 768, nullptr, T_,
            nullptr, nullptr, nullptr, nullptr, nullptr, nullptr);
        attn_kernel<<<B_ * H_, 256, 0, stream>>>(qkvb, ob,
                                                 wfreq + i * H_, wphase + i * H_);
        // o-proj + residual
        mfma_gemm<1, 0, 8><<<dim3(T_/128, 2, 1), 256, 0, stream>>>(
            ob, D_, wot + (size_t)i * 65536, 0, 256,
            nullptr, 0, h, D_, hb, T_,
            nullptr, nullptr, nullptr, nullptr, nullptr, nullptr);

        if (i % 2 == 0) {
            const int m = i / 2;
            const u16* w1t = ew1t + (size_t)m * NE_ * DFF_ * D_;
            const u16* w2t = ew2t + (size_t)m * NE_ * D_ * DFF_;
            const float* b1 = eb1 + (size_t)m * NE_ * DFF_;
            const float* b2 = eb2 + (size_t)m * NE_ * D_;
            router_kernel<<<T_ / 4, 256, 0, stream>>>(
                h, rtw + (size_t)m * D_ * NE_, rtb + m * NE_, te, twt);
            countscan_kernel<<<1, 512, 0, stream>>>(te, cnt, base_, cursor,
                                                    de, dr, ndesc);
            scatter_kernel<<<(2 * T_) / 512, 256, 0, stream>>>(te, base_, cursor,
                                                               atok, tslot);
            // w1: hidden[slot][1024] = gelu(hb[atok[slot]] @ w1 + b1)
            mfma_gemm<2, 1, 8><<<dim3(NDESC_MAX, DFF_/128, 1), 256, 0, stream>>>(
                hb, D_, w1t, (long)DFF_ * D_, 256,
                b1, DFF_, hidden, DFF_, nullptr, 0,
                cnt, base_, atok, de, dr, ndesc);
            // w2 over full K=1024: eo[slot][256] = hidden[slot] @ w2 + b2
            mfma_gemm<3, 2, 32><<<dim3(NDESC_MAX, D_/128, 1), 256, 0, stream>>>(
                hidden, DFF_, w2t, (long)D_ * DFF_, DFF_,
                b2, D_, eo, D_, nullptr, 0,
                cnt, base_, nullptr, de, dr, ndesc);
            combine_kernel<<<(T_ * 64) / 256, 256, 0, stream>>>(h, hb, eo,
                                                                twt, tslot);
        }
    }

    final_kernel<<<B_, 256, 0, stream>>>(h, ln_g, ln_b, pred_w, pred_b,
                                         unc_w, unc_b, (float*)d_out);
}

// Round 10
// 961.075 us; speedup vs baseline: 1.5141x; 1.5141x over previous
//
#include <hip/hip_runtime.h>
#include <hip/hip_bf16.h>
#include <math.h>

#define B_    128
#define L_    128
#define DIN   6
#define D_    256
#define H_    8
#define NL_   6
#define NE_   8
#define DFF_  1024
#define NOUT_ 5
#define T_    (B_*L_)      /* 16384 tokens */
#define DK_   32
#define ND256_MAX 136      /* 32768/256 + 8 experts ceil slack */
#define ND128_MAX 264      /* 32768/128 + 8 experts ceil slack */

typedef unsigned short u16;
typedef __hip_bfloat16 bf16;
typedef __attribute__((ext_vector_type(8))) short short8;
typedef __attribute__((ext_vector_type(8))) unsigned short ushort8v;
typedef __attribute__((ext_vector_type(4))) unsigned short ushort4v;
typedef __attribute__((ext_vector_type(4))) float floatx4;

// small f32 canon region: x, emb_w, emb_b, wfreq, wphase, rtw, rtb, eb1,
// eb2, ln_g, ln_b, pred_w, pred_b, unc_w, unc_b
__device__ const int S_PRE[16] = {
    0, 98304, 99840, 100096, 100144, 100192, 106336, 106360,
    130936, 137080, 137336, 137592, 138872, 138877, 140157, 140162};
__device__ const int S_SRC[15] = {0,1,2,7,8,9,10,12,14,15,16,17,18,19,20};
#define NSMALL 140162

struct SrcPtrs { const void* p[21]; };

__device__ __forceinline__ float bf2f(u16 u) {
    return __uint_as_float(((unsigned)u) << 16);
}
__device__ __forceinline__ u16 f2bf(float f) {
    union { bf16 b; u16 u; } c; c.b = __float2bfloat16(f); return c.u;
}
__device__ __forceinline__ float gelu_f(float x) {
    return 0.5f * x * (1.0f + erff(x * 0.70710678118654752f));
}

// async global->LDS, 16B per lane. LDS dest is wave-uniform base + lane*16.
__device__ __forceinline__ void gl_lds16(const u16* g, u16* l) {
    __builtin_amdgcn_global_load_lds(
        (const __attribute__((address_space(1))) unsigned int*)g,
        (__attribute__((address_space(3))) unsigned int*)l,
        16, 0, 0);
}

// ---------------------------------------------------------------------------
// Canonicalize small tensors to f32 (dtype probe: ln_g[0]==0x3F80 iff bf16)
// ---------------------------------------------------------------------------
__global__ __launch_bounds__(256)
void conv_small_kernel(SrcPtrs P, float* __restrict__ dst)
{
    const int i = blockIdx.x * 256 + threadIdx.x;
    if (i >= NSMALL) return;
    int seg = 0;
    #pragma unroll
    for (int s = 1; s < 15; ++s) seg += (i >= S_PRE[s]) ? 1 : 0;
    const int off = i - S_PRE[seg];
    const void* src = P.p[S_SRC[seg]];
    const bool isbf = (((const u16*)P.p[15])[0] == 0x3F80);
    if (isbf) dst[i] = bf2f(((const u16*)src)[off]);
    else      dst[i] = ((const float*)src)[off];
}

// ---------------------------------------------------------------------------
// TILED weight transpose+cast: dst[z][(n+noff)][k] = src[z][k][n], 64x64 tiles
// via LDS (R8-verified). grid: (z, KD/64, ND/64), 256 thr.
// ---------------------------------------------------------------------------
template<int KD, int ND>
__global__ __launch_bounds__(256)
void transpose_tiled(const void* __restrict__ src, const u16* __restrict__ probe,
                     u16* __restrict__ dst, long dzs, int noff)
{
    const int z  = blockIdx.x;
    const int k0 = blockIdx.y * 64;
    const int n0 = blockIdx.z * 64;
    __shared__ u16 tile[64][66];     // row len 66: <=4-way on column gather
    const int tid = threadIdx.x;
    const bool isbf = (probe[0] == 0x3F80);

    if (isbf) {
        const u16* s = (const u16*)src + (size_t)z * KD * ND + (size_t)k0 * ND + n0;
        #pragma unroll
        for (int p = 0; p < 2; ++p) {
            const int c  = p * 256 + tid;
            const int kk = c >> 3, nn = (c & 7) * 8;
            *(ushort8v*)&tile[kk][nn] = *(const ushort8v*)(s + (size_t)kk * ND + nn);
        }
    } else {
        const float* s = (const float*)src + (size_t)z * KD * ND + (size_t)k0 * ND + n0;
        #pragma unroll
        for (int p = 0; p < 2; ++p) {
            const int c  = p * 256 + tid;
            const int kk = c >> 3, nn = (c & 7) * 8;
            float4 v0 = *(const float4*)(s + (size_t)kk * ND + nn);
            float4 v1 = *(const float4*)(s + (size_t)kk * ND + nn + 4);
            ushort8v t;
            t[0]=f2bf(v0.x); t[1]=f2bf(v0.y); t[2]=f2bf(v0.z); t[3]=f2bf(v0.w);
            t[4]=f2bf(v1.x); t[5]=f2bf(v1.y); t[6]=f2bf(v1.z); t[7]=f2bf(v1.w);
            *(ushort8v*)&tile[kk][nn] = t;
        }
    }
    __syncthreads();

    u16* d = dst + (size_t)z * dzs + (size_t)(n0 + noff) * KD + k0;
    #pragma unroll
    for (int p = 0; p < 2; ++p) {
        const int c  = p * 256 + tid;
        const int nn = c >> 3, kk = (c & 7) * 8;
        ushort8v t;
        #pragma unroll
        for (int j = 0; j < 8; ++j) t[j] = tile[kk + j][nn];
        *(ushort8v*)&d[(size_t)nn * KD + kk] = t;
    }
}

// ---------------------------------------------------------------------------
// Embedding (all f32) + bf16 mirror
// ---------------------------------------------------------------------------
__global__ __launch_bounds__(256)
void embed_kernel(const float* __restrict__ x, const float* __restrict__ emb_w,
                  const float* __restrict__ emb_b, float* __restrict__ h,
                  u16* __restrict__ hb)
{
    const int idx = blockIdx.x * 256 + threadIdx.x;
    const int t = idx >> 8;
    const int d = idx & 255;
    float acc = emb_b[d];
    #pragma unroll
    for (int j = 0; j < DIN; ++j)
        acc += x[t * DIN + j] * emb_w[j * D_ + d];
    h[idx]  = acc;
    hb[idx] = f2bf(acc);
}

// ---------------------------------------------------------------------------
// MFMA GEMM 256x128 tile, 8 waves (R7/R8-verified: 66us w1, conflicts 0).
// 2-phase gl_lds double-buffer, one barrier/K-step. Used for QKV + MoE w1
// (large grids). R9's no-LDS variant proved the L2-request pipeline, not the
// barrier structure, is binding -> this is the scheduling-level floor.
// ---------------------------------------------------------------------------
template<int EPI, int MODE, int NT>
__global__ __launch_bounds__(512, 4)
void mfma_gemm256(const u16* __restrict__ A, int lda,
                  const u16* __restrict__ Wt, long wzs, int ldwt,
                  const float* __restrict__ biasb, long bzs,
                  void* __restrict__ CoutV, int ldc,
                  u16* __restrict__ hbout, int Mfixed,
                  const int* __restrict__ cnt, const int* __restrict__ base_,
                  const int* __restrict__ atok,
                  const int* __restrict__ de, const int* __restrict__ dr,
                  const int* __restrict__ ndesc)
{
    int M, r0, sbase = 0, e = 0;
    if constexpr (MODE == 0) {
        M  = Mfixed;
        r0 = blockIdx.x * 256;
        if (r0 >= M) return;
    } else {
        const int i = blockIdx.x;
        if (i >= *ndesc) return;
        e     = de[i];
        r0    = dr[i] * 256;
        sbase = base_[e];
        M     = cnt[e];
    }
    const u16*   W    = Wt + (size_t)e * wzs;
    const float* bias = biasb ? (biasb + (size_t)e * bzs) : nullptr;
    const int col0 = blockIdx.y * 128;

    __shared__ __attribute__((aligned(16))) u16 As[2][256 * 32];
    __shared__ __attribute__((aligned(16))) u16 Bs[2][128 * 32];
    __shared__ int stok[256];

    const int tid  = threadIdx.x;
    const int lane = tid & 63;
    const int wave = tid >> 6;            // 0..7
    const int wm = wave & 3, wn = wave >> 2;

    if constexpr (MODE == 1) {
        if (tid < 256) {
            int rr = r0 + tid;
            if (rr >= M) rr = M - 1;
            stok[tid] = atok[sbase + rr];
        }
        __syncthreads();
    }

    const int ss  = (lane & 3) ^ ((lane >> 3) & 3);
    const int rA0 = wave * 16 + (lane >> 2);        // pass-0 row (0..127)
    const int rA1 = rA0 + 128;                      // pass-1 row
    const int rB  = tid >> 2;                       // B col (0..127)
    long ar0, ar1;
    if constexpr (MODE == 1) {
        ar0 = stok[rA0];
        ar1 = stok[rA1];
    } else {
        int rr0 = r0 + rA0; if (rr0 >= M) rr0 = M - 1;
        int rr1 = r0 + rA1; if (rr1 >= M) rr1 = M - 1;
        ar0 = (MODE == 2) ? (long)(sbase + rr0) : (long)rr0;
        ar1 = (MODE == 2) ? (long)(sbase + rr1) : (long)rr1;
    }
    const u16* ga0 = A + ar0 * (long)lda + ss * 8;
    const u16* ga1 = A + ar1 * (long)lda + ss * 8;
    const u16* gw0 = W + (size_t)(col0 + rB) * ldwt + ss * 8;

    floatx4 acc[4][4];
    #pragma unroll
    for (int i = 0; i < 4; ++i)
        #pragma unroll
        for (int j = 0; j < 4; ++j)
            acc[i][j] = (floatx4){0.f, 0.f, 0.f, 0.f};

    const int fm = wm * 64 + (lane & 15);           // A row (0..255)
    const int fn = wn * 64 + (lane & 15);           // B col (0..127)
    const int ps = (lane >> 4) ^ ((lane >> 1) & 3); // reader phys slot

    auto STAGE = [&](int b, int kt) {
        const int ko = kt * 32;
        gl_lds16(ga0 + ko, &As[b][wave * 512 + lane * 8]);
        gl_lds16(ga1 + ko, &As[b][4096 + wave * 512 + lane * 8]);
        gl_lds16(gw0 + ko, &Bs[b][wave * 512 + lane * 8]);
    };

    STAGE(0, 0);
    __syncthreads();

    int buf = 0;
    for (int t = 0; t < NT; ++t) {
        if (t + 1 < NT) STAGE(buf ^ 1, t + 1);

        short8 af[4], bfr[4];
        #pragma unroll
        for (int i = 0; i < 4; ++i)
            af[i]  = *(const short8*)&As[buf][(fm + 16 * i) * 32 + ps * 8];
        #pragma unroll
        for (int j = 0; j < 4; ++j)
            bfr[j] = *(const short8*)&Bs[buf][(fn + 16 * j) * 32 + ps * 8];
        #pragma unroll
        for (int i = 0; i < 4; ++i)
            #pragma unroll
            for (int j = 0; j < 4; ++j)
                acc[i][j] = __builtin_amdgcn_mfma_f32_16x16x32_bf16(
                    af[i], bfr[j], acc[i][j], 0, 0, 0);

        __syncthreads();
        buf ^= 1;
    }

    const int er = wm * 64 + ((lane >> 4) << 2);
    const int ec = wn * 64 + (lane & 15);
    #pragma unroll
    for (int i = 0; i < 4; ++i) {
        #pragma unroll
        for (int reg = 0; reg < 4; ++reg) {
            const int lrow = r0 + er + i * 16 + reg;
            if (lrow >= M) continue;
            const long crow = (MODE == 0) ? (long)lrow : (long)(sbase + lrow);
            #pragma unroll
            for (int j = 0; j < 4; ++j) {
                const int cj = col0 + ec + j * 16;
                const float val = acc[i][j][reg];
                if constexpr (EPI == 0) {
                    ((u16*)CoutV)[crow * ldc + cj] = f2bf(val);
                } else if constexpr (EPI == 1) {
                    const size_t idx = crow * ldc + cj;
                    const float nv = ((float*)CoutV)[idx] + val;
                    ((float*)CoutV)[idx] = nv;
                    hbout[idx] = f2bf(nv);
                } else if constexpr (EPI == 2) {
                    ((u16*)CoutV)[crow * ldc + cj] = f2bf(gelu_f(val + bias[cj]));
                } else {
                    ((float*)CoutV)[crow * ldc + cj] = val + bias[cj];
                }
            }
        }
    }
}

// ---------------------------------------------------------------------------
// MFMA GEMM 128x128 tile, 4 waves (R4-verified: 69us w1, conflicts 0).
// Same 2-phase schedule. Used for the SMALL-GRID GEMMs (o-proj, MoE w2):
// R8's 256-row tiles gave o-proj only 128 blocks (half the CUs idle) and
// w2 272 blocks (~1 block/CU, no overlap); this doubles those grids.
// ---------------------------------------------------------------------------
template<int EPI, int MODE, int NT>
__global__ __launch_bounds__(256)
void mfma_gemm128(const u16* __restrict__ A, int lda,
                  const u16* __restrict__ Wt, long wzs, int ldwt,
                  const float* __restrict__ biasb, long bzs,
                  void* __restrict__ CoutV, int ldc,
                  u16* __restrict__ hbout, int Mfixed,
                  const int* __restrict__ cnt, const int* __restrict__ base_,
                  const int* __restrict__ atok,
                  const int* __restrict__ de, const int* __restrict__ dr,
                  const int* __restrict__ ndesc)
{
    int M, r0, sbase = 0, e = 0;
    if constexpr (MODE == 0) {
        M  = Mfixed;
        r0 = blockIdx.x * 128;
        if (r0 >= M) return;
    } else {
        const int i = blockIdx.x;
        if (i >= *ndesc) return;
        e     = de[i];
        r0    = dr[i] * 128;
        sbase = base_[e];
        M     = cnt[e];
    }
    const u16*   W    = Wt + (size_t)e * wzs;
    const float* bias = biasb ? (biasb + (size_t)e * bzs) : nullptr;
    const int col0 = blockIdx.y * 128;

    __shared__ __attribute__((aligned(16))) u16 As[2][128 * 32];
    __shared__ __attribute__((aligned(16))) u16 Bs[2][128 * 32];
    __shared__ int stok[128];

    const int tid  = threadIdx.x;
    const int lane = tid & 63;
    const int wave = tid >> 6;
    const int wm = wave & 1, wn = wave >> 1;

    if constexpr (MODE == 1) {
        if (tid < 128) {
            int rr = r0 + tid;
            if (rr >= M) rr = M - 1;
            stok[tid] = atok[sbase + rr];
        }
        __syncthreads();
    }

    // staging: thread covers 2 chunks (rows wave*16+(lane>>2) and +64)
    const int ss   = (lane & 3) ^ ((lane >> 3) & 3);
    const int row0 = wave * 16 + (lane >> 2);
    const int row1 = row0 + 64;
    long ar0, ar1;
    if constexpr (MODE == 1) {
        ar0 = stok[row0];
        ar1 = stok[row1];
    } else {
        int rr0 = r0 + row0; if (rr0 >= M) rr0 = M - 1;
        int rr1 = r0 + row1; if (rr1 >= M) rr1 = M - 1;
        ar0 = (MODE == 2) ? (long)(sbase + rr0) : (long)rr0;
        ar1 = (MODE == 2) ? (long)(sbase + rr1) : (long)rr1;
    }
    const u16* ga0 = A + ar0 * (long)lda + ss * 8;
    const u16* ga1 = A + ar1 * (long)lda + ss * 8;
    const u16* gw0 = W + (size_t)(col0 + row0) * ldwt + ss * 8;
    const u16* gw1 = W + (size_t)(col0 + row1) * ldwt + ss * 8;

    floatx4 acc[4][4];
    #pragma unroll
    for (int i = 0; i < 4; ++i)
        #pragma unroll
        for (int j = 0; j < 4; ++j)
            acc[i][j] = (floatx4){0.f, 0.f, 0.f, 0.f};

    const int fm = wm * 64 + (lane & 15);
    const int fn = wn * 64 + (lane & 15);
    const int ps = (lane >> 4) ^ ((lane >> 1) & 3);

    auto STAGE = [&](int b, int kt) {
        const int ko = kt * 32;
        gl_lds16(ga0 + ko, &As[b][tid * 8]);
        gl_lds16(ga1 + ko, &As[b][2048 + tid * 8]);
        gl_lds16(gw0 + ko, &Bs[b][tid * 8]);
        gl_lds16(gw1 + ko, &Bs[b][2048 + tid * 8]);
    };

    STAGE(0, 0);
    __syncthreads();

    int buf = 0;
    for (int t = 0; t < NT; ++t) {
        if (t + 1 < NT) STAGE(buf ^ 1, t + 1);

        short8 af[4], bfr[4];
        #pragma unroll
        for (int i = 0; i < 4; ++i)
            af[i]  = *(const short8*)&As[buf][(fm + 16 * i) * 32 + ps * 8];
        #pragma unroll
        for (int j = 0; j < 4; ++j)
            bfr[j] = *(const short8*)&Bs[buf][(fn + 16 * j) * 32 + ps * 8];
        #pragma unroll
        for (int i = 0; i < 4; ++i)
            #pragma unroll
            for (int j = 0; j < 4; ++j)
                acc[i][j] = __builtin_amdgcn_mfma_f32_16x16x32_bf16(
                    af[i], bfr[j], acc[i][j], 0, 0, 0);

        __syncthreads();
        buf ^= 1;
    }

    const int er = wm * 64 + ((lane >> 4) << 2);
    const int ec = wn * 64 + (lane & 15);
    #pragma unroll
    for (int i = 0; i < 4; ++i) {
        #pragma unroll
        for (int reg = 0; reg < 4; ++reg) {
            const int lrow = r0 + er + i * 16 + reg;
            if (lrow >= M) continue;
            const long crow = (MODE == 0) ? (long)lrow : (long)(sbase + lrow);
            #pragma unroll
            for (int j = 0; j < 4; ++j) {
                const int cj = col0 + ec + j * 16;
                const float val = acc[i][j][reg];
                if constexpr (EPI == 0) {
                    ((u16*)CoutV)[crow * ldc + cj] = f2bf(val);
                } else if constexpr (EPI == 1) {
                    const size_t idx = crow * ldc + cj;
                    const float nv = ((float*)CoutV)[idx] + val;
                    ((float*)CoutV)[idx] = nv;
                    hbout[idx] = f2bf(nv);
                } else if constexpr (EPI == 2) {
                    ((u16*)CoutV)[crow * ldc + cj] = f2bf(gelu_f(val + bias[cj]));
                } else {
                    ((float*)CoutV)[crow * ldc + cj] = val + bias[cj];
                }
            }
        }
    }
}

// ---------------------------------------------------------------------------
// MFMA wave attention, one block (256 thr, 4 waves) per (b, head).
// ---------------------------------------------------------------------------
__global__ __launch_bounds__(256)
void attn_kernel(const u16* __restrict__ qkv, u16* __restrict__ o,
                 const float* __restrict__ wfreq, const float* __restrict__ wphase)
{
    const int bh = blockIdx.x;
    const int b  = bh >> 3;
    const int hh = bh & 7;

    __shared__ __attribute__((aligned(16))) u16 Qs[128][40];
    __shared__ __attribute__((aligned(16))) u16 Ks[128][40];
    __shared__ __attribute__((aligned(16))) u16 Vt[32][136];
    __shared__ __attribute__((aligned(16))) u16 Ps[128][136];
    __shared__ float wavec[128];

    const int tid  = threadIdx.x;
    const int lane = tid & 63;
    const int w    = tid >> 6;
    const int col16 = lane & 15;
    const int quad  = lane >> 4;

    const long qbase = (long)b * L_ * 768 + hh * DK_;

    // stage Q, K, V^T (bf16)
    {
        const int row = tid >> 1;
        const int hf  = (tid & 1) * 16;
        const u16* src = qkv + qbase + (long)row * 768 + hf;
        *(ushort8v*)&Qs[row][hf]     = *(const ushort8v*)(src);
        *(ushort8v*)&Qs[row][hf + 8] = *(const ushort8v*)(src + 8);
        *(ushort8v*)&Ks[row][hf]     = *(const ushort8v*)(src + 256);
        *(ushort8v*)&Ks[row][hf + 8] = *(const ushort8v*)(src + 264);
        #pragma unroll
        for (int j = 0; j < 16; ++j)
            Vt[hf + j][row] = src[512 + j];
    }
    if (tid < L_) {
        float f2 = 6.2831853071795864769f * wfreq[hh];
        wavec[tid] = cosf(f2 * (float)tid + wphase[hh]);
    }
    __syncthreads();

    const float scale = 0.17677669529663687f;   // 1/sqrt(32)
    float wv8[8];
    #pragma unroll
    for (int ni = 0; ni < 8; ++ni)
        wv8[ni] = scale * wavec[ni * 16 + col16];

    // S = Q K^T : wave w owns rows [w*32, w*32+32)
    const int m0 = w * 32;
    floatx4 accs[2][8];
    {
        short8 a0 = *(const short8*)&Qs[m0 + col16][quad * 8];
        short8 a1 = *(const short8*)&Qs[m0 + 16 + col16][quad * 8];
        #pragma unroll
        for (int ni = 0; ni < 8; ++ni) {
            short8 bf = *(const short8*)&Ks[ni * 16 + col16][quad * 8];
            accs[0][ni] = __builtin_amdgcn_mfma_f32_16x16x32_bf16(
                a0, bf, (floatx4){0.f,0.f,0.f,0.f}, 0, 0, 0);
            accs[1][ni] = __builtin_amdgcn_mfma_f32_16x16x32_bf16(
                a1, bf, (floatx4){0.f,0.f,0.f,0.f}, 0, 0, 0);
        }
    }
    #pragma unroll
    for (int mi = 0; mi < 2; ++mi)
        #pragma unroll
        for (int ni = 0; ni < 8; ++ni)
            #pragma unroll
            for (int reg = 0; reg < 4; ++reg)
                accs[mi][ni][reg] *= wv8[ni];

    // full-row softmax: row = m0 + mi*16 + quad*4 + reg, in-wave
    #pragma unroll
    for (int mi = 0; mi < 2; ++mi) {
        #pragma unroll
        for (int reg = 0; reg < 4; ++reg) {
            float rmax = -1e30f;
            #pragma unroll
            for (int ni = 0; ni < 8; ++ni)
                rmax = fmaxf(rmax, accs[mi][ni][reg]);
            #pragma unroll
            for (int off = 1; off < 16; off <<= 1)
                rmax = fmaxf(rmax, __shfl_xor(rmax, off));
            float e[8], rsum = 0.0f;
            #pragma unroll
            for (int ni = 0; ni < 8; ++ni) {
                e[ni] = expf(accs[mi][ni][reg] - rmax);
                rsum += e[ni];
            }
            #pragma unroll
            for (int off = 1; off < 16; off <<= 1)
                rsum += __shfl_xor(rsum, off);
            const float inv = 1.0f / rsum;
            const int row = m0 + mi * 16 + quad * 4 + reg;
            #pragma unroll
            for (int ni = 0; ni < 8; ++ni)
                Ps[row][ni * 16 + col16] = f2bf(e[ni] * inv);
        }
    }
    __syncthreads();

    // O = P V
    floatx4 acco[2][2];
    #pragma unroll
    for (int mi = 0; mi < 2; ++mi)
        #pragma unroll
        for (int nj = 0; nj < 2; ++nj)
            acco[mi][nj] = (floatx4){0.f,0.f,0.f,0.f};
    #pragma unroll
    for (int kk = 0; kk < 4; ++kk) {
        short8 a0 = *(const short8*)&Ps[m0 + col16][kk * 32 + quad * 8];
        short8 a1 = *(const short8*)&Ps[m0 + 16 + col16][kk * 32 + quad * 8];
        short8 b0 = *(const short8*)&Vt[col16][kk * 32 + quad * 8];
        short8 b1 = *(const short8*)&Vt[16 + col16][kk * 32 + quad * 8];
        acco[0][0] = __builtin_amdgcn_mfma_f32_16x16x32_bf16(a0, b0, acco[0][0], 0, 0, 0);
        acco[0][1] = __builtin_amdgcn_mfma_f32_16x16x32_bf16(a0, b1, acco[0][1], 0, 0, 0);
        acco[1][0] = __builtin_amdgcn_mfma_f32_16x16x32_bf16(a1, b0, acco[1][0], 0, 0, 0);
        acco[1][1] = __builtin_amdgcn_mfma_f32_16x16x32_bf16(a1, b1, acco[1][1], 0, 0, 0);
    }

    const long obase = (long)b * L_ * D_ + hh * DK_;
    #pragma unroll
    for (int mi = 0; mi < 2; ++mi)
        #pragma unroll
        for (int reg = 0; reg < 4; ++reg) {
            const int row = m0 + mi * 16 + quad * 4 + reg;
            #pragma unroll
            for (int nj = 0; nj < 2; ++nj)
                o[obase + (long)row * D_ + nj * 16 + col16] =
                    f2bf(acco[mi][nj][reg]);
        }
}

// ---------------------------------------------------------------------------
// MoE router: one WAVE per token.
// ---------------------------------------------------------------------------
__global__ __launch_bounds__(256)
void router_kernel(const float* __restrict__ h, const float* __restrict__ rtw,
                   const float* __restrict__ rtb, int* __restrict__ te,
                   float* __restrict__ twt)
{
    const int tid  = threadIdx.x;
    const int lane = tid & 63;
    const int wv   = tid >> 6;
    const int t    = blockIdx.x * 4 + wv;

    const float4 hv = ((const float4*)(h + (long)t * D_))[lane];
    const float4* rp = (const float4*)rtw;

    float lg[NE_];
    #pragma unroll
    for (int e = 0; e < NE_; ++e) lg[e] = 0.0f;
    #pragma unroll
    for (int i = 0; i < 4; ++i) {
        const int d = lane * 4 + i;
        const float xv = (i == 0) ? hv.x : (i == 1) ? hv.y : (i == 2) ? hv.z : hv.w;
        float4 wa = rp[d * 2 + 0];
        float4 wb = rp[d * 2 + 1];
        lg[0] = fmaf(xv, wa.x, lg[0]);
        lg[1] = fmaf(xv, wa.y, lg[1]);
        lg[2] = fmaf(xv, wa.z, lg[2]);
        lg[3] = fmaf(xv, wa.w, lg[3]);
        lg[4] = fmaf(xv, wb.x, lg[4]);
        lg[5] = fmaf(xv, wb.y, lg[5]);
        lg[6] = fmaf(xv, wb.z, lg[6]);
        lg[7] = fmaf(xv, wb.w, lg[7]);
    }
    #pragma unroll
    for (int off = 1; off < 64; off <<= 1)
        #pragma unroll
        for (int e = 0; e < NE_; ++e)
            lg[e] += __shfl_xor(lg[e], off);

    if (lane == 0) {
        #pragma unroll
        for (int e = 0; e < NE_; ++e) lg[e] += rtb[e];
        int i1 = 0; float v1 = lg[0];
        #pragma unroll
        for (int e = 1; e < NE_; ++e) { if (lg[e] > v1) { v1 = lg[e]; i1 = e; } }
        int i2 = (i1 == 0) ? 1 : 0; float v2 = lg[i2];
        #pragma unroll
        for (int e = 0; e < NE_; ++e) {
            if (e != i1 && lg[e] > v2) { v2 = lg[e]; i2 = e; }
        }
        float r   = expf(v2 - v1);
        float wa1 = 1.0f / (1.0f + r);
        te[2 * t]     = i1;
        te[2 * t + 1] = i2;
        twt[2 * t]     = wa1;
        twt[2 * t + 1] = r * wa1;
    }
}

// ---------------------------------------------------------------------------
// Count experts + exclusive scan + zero cursors + BOTH descriptor sets
// (256-row for w1's 8-wave kernel, 128-row for w2's 4-wave kernel).
// ---------------------------------------------------------------------------
__global__ __launch_bounds__(512)
void countscan_kernel(const int* __restrict__ te, int* __restrict__ cnt,
                      int* __restrict__ base_, int* __restrict__ cursor,
                      int* __restrict__ de, int* __restrict__ dr,
                      int* __restrict__ ndesc,
                      int* __restrict__ de2, int* __restrict__ dr2,
                      int* __restrict__ ndesc2)
{
    const int tid = threadIdx.x;
    int c[NE_];
    #pragma unroll
    for (int e = 0; e < NE_; ++e) c[e] = 0;
    for (int i = tid; i < 2 * T_; i += 512) {
        const int e = te[i];
        #pragma unroll
        for (int ee = 0; ee < NE_; ++ee) c[ee] += (e == ee) ? 1 : 0;
    }
    #pragma unroll
    for (int off = 1; off < 64; off <<= 1)
        #pragma unroll
        for (int e = 0; e < NE_; ++e)
            c[e] += __shfl_xor(c[e], off);

    __shared__ int wsum[8][NE_];
    const int lane = tid & 63, wv = tid >> 6;
    if (lane == 0)
        #pragma unroll
        for (int e = 0; e < NE_; ++e) wsum[wv][e] = c[e];
    __syncthreads();
    if (tid == 0) {
        int a = 0, n = 0, n2 = 0;
        for (int e = 0; e < NE_; ++e) {
            int s = 0;
            for (int w = 0; w < 8; ++w) s += wsum[w][e];
            cnt[e] = s;
            base_[e] = a;
            a += s;
            const int nb = (s + 255) >> 8;
            for (int rb = 0; rb < nb; ++rb) { de[n] = e; dr[n] = rb; ++n; }
            const int nb2 = (s + 127) >> 7;
            for (int rb = 0; rb < nb2; ++rb) { de2[n2] = e; dr2[n2] = rb; ++n2; }
        }
        *ndesc  = n;
        *ndesc2 = n2;
    }
    if (tid < NE_) cursor[tid] = 0;
}

// ---------------------------------------------------------------------------
// Scatter with LDS rank aggregation: 8 global atomics per block.
// ---------------------------------------------------------------------------
__global__ __launch_bounds__(256)
void scatter_kernel(const int* __restrict__ te, const int* __restrict__ base_,
                    int* __restrict__ cursor, int* __restrict__ atok,
                    int* __restrict__ tslot)
{
    __shared__ int lcnt[NE_];
    __shared__ int gb[NE_];
    const int tid = threadIdx.x;
    if (tid < NE_) lcnt[tid] = 0;
    __syncthreads();

    const int i0 = blockIdx.x * 512 + tid * 2;
    const int e0 = te[i0], e1 = te[i0 + 1];
    const int r0 = atomicAdd(&lcnt[e0], 1);
    const int r1 = atomicAdd(&lcnt[e1], 1);
    __syncthreads();
    if (tid < NE_) gb[tid] = atomicAdd(&cursor[tid], lcnt[tid]);
    __syncthreads();

    const int s0 = base_[e0] + gb[e0] + r0;
    const int s1 = base_[e1] + gb[e1] + r1;
    atok[s0] = i0 >> 1;
    atok[s1] = i0 >> 1;
    tslot[i0]     = s0;
    tslot[i0 + 1] = s1;
}

// ---------------------------------------------------------------------------
// Combine, vectorized: f32x4 per thread (R8-verified).
// ---------------------------------------------------------------------------
__global__ __launch_bounds__(256)
void combine_kernel(float* __restrict__ h, u16* __restrict__ hb,
                    const float* __restrict__ eo,
                    const float* __restrict__ twt, const int* __restrict__ tslot)
{
    const int i = blockIdx.x * 256 + threadIdx.x;
    const int t = i >> 6;                 // token
    const int g = i & 63;                 // f32x4 group within row (D/4=64)
    const int s0 = tslot[2 * t], s1 = tslot[2 * t + 1];
    const float w0 = twt[2 * t], w1 = twt[2 * t + 1];
    float4 a  = ((const float4*)(eo + (size_t)s0 * D_))[g];
    float4 b  = ((const float4*)(eo + (size_t)s1 * D_))[g];
    float4 hv = ((const float4*)(h + (size_t)t * D_))[g];
    hv.x += w0 * a.x + w1 * b.x;
    hv.y += w0 * a.y + w1 * b.y;
    hv.z += w0 * a.z + w1 * b.z;
    hv.w += w0 * a.w + w1 * b.w;
    ((float4*)(h + (size_t)t * D_))[g] = hv;
    ushort4v pk;
    pk[0] = f2bf(hv.x); pk[1] = f2bf(hv.y); pk[2] = f2bf(hv.z); pk[3] = f2bf(hv.w);
    *(ushort4v*)&hb[(size_t)t * D_ + g * 4] = pk;
}

// ---------------------------------------------------------------------------
// Final: LN on last-position tokens, pred / softplus heads. f32 output.
// ---------------------------------------------------------------------------
__global__ __launch_bounds__(256)
void final_kernel(const float* __restrict__ h, const float* __restrict__ ln_g,
                  const float* __restrict__ ln_b, const float* __restrict__ pred_w,
                  const float* __restrict__ pred_b, const float* __restrict__ unc_w,
                  const float* __restrict__ unc_b, float* __restrict__ out)
{
    const int b = blockIdx.x;
    const int d = threadIdx.x;
    const long t = (long)b * L_ + (L_ - 1);
    const float val = h[t * D_ + d];

    __shared__ float red[4];
    __shared__ float lat[D_];

    float s = val;
    #pragma unroll
    for (int off = 32; off > 0; off >>= 1) s += __shfl_down(s, off);
    if ((d & 63) == 0) red[d >> 6] = s;
    __syncthreads();
    const float mean = (red[0] + red[1] + red[2] + red[3]) * (1.0f / D_);
    __syncthreads();

    const float dv = val - mean;
    s = dv * dv;
    #pragma unroll
    for (int off = 32; off > 0; off >>= 1) s += __shfl_down(s, off);
    if ((d & 63) == 0) red[d >> 6] = s;
    __syncthreads();
    const float var = (red[0] + red[1] + red[2] + red[3]) * (1.0f / D_);

    lat[d] = dv * rsqrtf(var + 1e-5f) * ln_g[d] + ln_b[d];
    __syncthreads();

    if (d < 2 * NOUT_) {
        const int j = d % NOUT_;
        const int sel = d / NOUT_;
        const float* w  = sel ? unc_w : pred_w;
        const float* bb = sel ? unc_b : pred_b;
        float acc = bb[j];
        for (int dd = 0; dd < D_; ++dd)
            acc = fmaf(lat[dd], w[dd * NOUT_ + j], acc);
        if (sel) acc = log1pf(expf(acc));
        out[sel * (B_ * NOUT_) + b * NOUT_ + j] = acc;
    }
}

// ---------------------------------------------------------------------------
extern "C" void kernel_launch(void* const* d_in, const int* in_sizes, int n_in,
                              void* d_out, int out_size, void* d_ws, size_t ws_size,
                              hipStream_t stream)
{
    (void)in_sizes; (void)n_in; (void)out_size; (void)ws_size;

    char* ws = (char*)d_ws;
    size_t off = 0;
    auto alloc = [&](size_t bytes) {
        size_t cur = off;
        off += (bytes + 255) & ~(size_t)255;
        return (void*)(ws + cur);
    };
    float* cs     = (float*)alloc((size_t)NSMALL * 4);
    u16*   qkvt   = (u16*)  alloc((size_t)NL_ * 768 * 256 * 2);
    u16*   wot    = (u16*)  alloc((size_t)NL_ * 256 * 256 * 2);
    u16*   ew1t   = (u16*)  alloc((size_t)3 * NE_ * DFF_ * D_ * 2);
    u16*   ew2t   = (u16*)  alloc((size_t)3 * NE_ * D_ * DFF_ * 2);
    float* h      = (float*)alloc((size_t)T_ * D_ * 4);
    u16*   hb     = (u16*)  alloc((size_t)T_ * D_ * 2);
    // union region: attn-phase {qkvb, ob} aliases moe-phase {hidden, eo}
    char*  uni    = (char*) alloc((size_t)2 * T_ * DFF_ * 2 + (size_t)2 * T_ * D_ * 4);
    u16*   qkvb   = (u16*)  uni;                                    // 25.2 MB
    u16*   ob     = (u16*)  (uni + (size_t)T_ * 768 * 2 + 256);     //  8.4 MB
    u16*   hidden = (u16*)  uni;                                    // 67.1 MB
    float* eo     = (float*)(uni + (size_t)2 * T_ * DFF_ * 2);      // 33.6 MB
    int*   te     = (int*)  alloc((size_t)2 * T_ * 4);
    float* twt    = (float*)alloc((size_t)2 * T_ * 4);
    int*   atok   = (int*)  alloc((size_t)2 * T_ * 4);
    int*   tslot  = (int*)  alloc((size_t)2 * T_ * 4);
    int*   cnt    = (int*)  alloc(64 * 4);
    int*   base_  = (int*)  alloc(64 * 4);
    int*   cursor = (int*)  alloc(64 * 4);
    int*   de     = (int*)  alloc(ND256_MAX * 4);
    int*   dr     = (int*)  alloc(ND256_MAX * 4);
    int*   ndesc  = (int*)  alloc(64 * 4);
    int*   de2    = (int*)  alloc(ND128_MAX * 4);
    int*   dr2    = (int*)  alloc(ND128_MAX * 4);
    int*   ndesc2 = (int*)  alloc(64 * 4);

    SrcPtrs P;
    for (int i = 0; i < 21; ++i) P.p[i] = d_in[i];
    const u16* probe = (const u16*)d_in[15];

    conv_small_kernel<<<(NSMALL + 255) / 256, 256, 0, stream>>>(P, cs);
    transpose_tiled<256,256><<<dim3(NL_, 4, 4), 256, 0, stream>>>(
        d_in[3], probe, qkvt, 768L * 256, 0);
    transpose_tiled<256,256><<<dim3(NL_, 4, 4), 256, 0, stream>>>(
        d_in[4], probe, qkvt, 768L * 256, 256);
    transpose_tiled<256,256><<<dim3(NL_, 4, 4), 256, 0, stream>>>(
        d_in[5], probe, qkvt, 768L * 256, 512);
    transpose_tiled<256,256><<<dim3(NL_, 4, 4), 256, 0, stream>>>(
        d_in[6], probe, wot, 65536L, 0);
    transpose_tiled<256,1024><<<dim3(24, 4, 16), 256, 0, stream>>>(
        d_in[11], probe, ew1t, 262144L, 0);
    transpose_tiled<1024,256><<<dim3(24, 16, 4), 256, 0, stream>>>(
        d_in[13], probe, ew2t, 262144L, 0);

    const float* x      = cs;
    const float* emb_w  = cs + 98304;
    const float* emb_b  = cs + 99840;
    const float* wfreq  = cs + 100096;
    const float* wphase = cs + 100144;
    const float* rtw    = cs + 100192;
    const float* rtb    = cs + 106336;
    const float* eb1    = cs + 106360;
    const float* eb2    = cs + 130936;
    const float* ln_g   = cs + 137080;
    const float* ln_b   = cs + 137336;
    const float* pred_w = cs + 137592;
    const float* pred_b = cs + 138872;
    const float* unc_w  = cs + 138877;
    const float* unc_b  = cs + 140157;

    embed_kernel<<<(T_ * D_) / 256, 256, 0, stream>>>(x, emb_w, emb_b, h, hb);

    for (int i = 0; i < NL_; ++i) {
        // QKV: [16384 x 768] = hb[16384 x 256] @ qkvt^T   (256-tile, big grid)
        mfma_gemm256<0, 0, 8><<<dim3(T_/256, 6, 1), 512, 0, stream>>>(
            hb, D_, qkvt + (size_t)i * 768 * 256, 0, 256,
            nullptr, 0, qkvb, 768, nullptr, T_,
            nullptr, nullptr, nullptr, nullptr, nullptr, nullptr);
        attn_kernel<<<B_ * H_, 256, 0, stream>>>(qkvb, ob,
                                                 wfreq + i * H_, wphase + i * H_);
        // o-proj + residual (128-tile: 256 blocks -> all CUs busy)
        mfma_gemm128<1, 0, 8><<<dim3(T_/128, 2, 1), 256, 0, stream>>>(
            ob, D_, wot + (size_t)i * 65536, 0, 256,
            nullptr, 0, h, D_, hb, T_,
            nullptr, nullptr, nullptr, nullptr, nullptr, nullptr);

        if (i % 2 == 0) {
            const int m = i / 2;
            const u16* w1t = ew1t + (size_t)m * NE_ * DFF_ * D_;
            const u16* w2t = ew2t + (size_t)m * NE_ * D_ * DFF_;
            const float* b1 = eb1 + (size_t)m * NE_ * DFF_;
            const float* b2 = eb2 + (size_t)m * NE_ * D_;
            router_kernel<<<T_ / 4, 256, 0, stream>>>(
                h, rtw + (size_t)m * D_ * NE_, rtb + m * NE_, te, twt);
            countscan_kernel<<<1, 512, 0, stream>>>(te, cnt, base_, cursor,
                                                    de, dr, ndesc,
                                                    de2, dr2, ndesc2);
            scatter_kernel<<<(2 * T_) / 512, 256, 0, stream>>>(te, base_, cursor,
                                                               atok, tslot);
            // w1: hidden[slot][1024] = gelu(hb[atok[slot]] @ w1 + b1)
            mfma_gemm256<2, 1, 8><<<dim3(ND256_MAX, DFF_/128, 1), 512, 0, stream>>>(
                hb, D_, w1t, (long)DFF_ * D_, 256,
                b1, DFF_, hidden, DFF_, nullptr, 0,
                cnt, base_, atok, de, dr, ndesc);
            // w2 over full K=1024 (128-tile: ~528 blocks vs 272 at 256-tile)
            mfma_gemm128<3, 2, 32><<<dim3(ND128_MAX, D_/128, 1), 256, 0, stream>>>(
                hidden, DFF_, w2t, (long)D_ * DFF_, DFF_,
                b2, D_, eo, D_, nullptr, 0,
                cnt, base_, nullptr, de2, dr2, ndesc2);
            combine_kernel<<<(T_ * 64) / 256, 256, 0, stream>>>(h, hb, eo,
                                                                twt, tslot);
        }
    }

    final_kernel<<<B_, 256, 0, stream>>>(h, ln_g, ln_b, pred_w, pred_b,
                                         unc_w, unc_b, (float*)d_out);
}

// Round 11
// 934.311 us; speedup vs baseline: 1.5575x; 1.0286x over previous
//
#include <hip/hip_runtime.h>
#include <hip/hip_bf16.h>
#include <math.h>

#define B_    128
#define L_    128
#define DIN   6
#define D_    256
#define H_    8
#define NL_   6
#define NE_   8
#define DFF_  1024
#define NOUT_ 5
#define T_    (B_*L_)      /* 16384 tokens */
#define DK_   32
#define NDESC_MAX 136      /* 32768/256 + 8 experts ceil slack */

typedef unsigned short u16;
typedef __hip_bfloat16 bf16;
typedef __attribute__((ext_vector_type(8))) short short8;
typedef __attribute__((ext_vector_type(8))) unsigned short ushort8v;
typedef __attribute__((ext_vector_type(4))) unsigned short ushort4v;
typedef __attribute__((ext_vector_type(4))) float floatx4;

// small f32 canon region: x, emb_w, emb_b, wfreq, wphase, rtw, rtb, eb1,
// eb2, ln_g, ln_b, pred_w, pred_b, unc_w, unc_b
__device__ const int S_PRE[16] = {
    0, 98304, 99840, 100096, 100144, 100192, 106336, 106360,
    130936, 137080, 137336, 137592, 138872, 138877, 140157, 140162};
__device__ const int S_SRC[15] = {0,1,2,7,8,9,10,12,14,15,16,17,18,19,20};
#define NSMALL 140162

struct SrcPtrs { const void* p[21]; };

__device__ __forceinline__ float bf2f(u16 u) {
    return __uint_as_float(((unsigned)u) << 16);
}
__device__ __forceinline__ u16 f2bf(float f) {
    union { bf16 b; u16 u; } c; c.b = __float2bfloat16(f); return c.u;
}
__device__ __forceinline__ float gelu_f(float x) {
    return 0.5f * x * (1.0f + erff(x * 0.70710678118654752f));
}

// async global->LDS, 16B per lane. LDS dest is wave-uniform base + lane*16.
__device__ __forceinline__ void gl_lds16(const u16* g, u16* l) {
    __builtin_amdgcn_global_load_lds(
        (const __attribute__((address_space(1))) unsigned int*)g,
        (__attribute__((address_space(3))) unsigned int*)l,
        16, 0, 0);
}

// ---------------------------------------------------------------------------
// Canonicalize small tensors to f32 (dtype probe: ln_g[0]==0x3F80 iff bf16)
// ---------------------------------------------------------------------------
__global__ __launch_bounds__(256)
void conv_small_kernel(SrcPtrs P, float* __restrict__ dst)
{
    const int i = blockIdx.x * 256 + threadIdx.x;
    if (i >= NSMALL) return;
    int seg = 0;
    #pragma unroll
    for (int s = 1; s < 15; ++s) seg += (i >= S_PRE[s]) ? 1 : 0;
    const int off = i - S_PRE[seg];
    const void* src = P.p[S_SRC[seg]];
    const bool isbf = (((const u16*)P.p[15])[0] == 0x3F80);
    if (isbf) dst[i] = bf2f(((const u16*)src)[off]);
    else      dst[i] = ((const float*)src)[off];
}

// ---------------------------------------------------------------------------
// TILED weight transpose+cast: dst[z][(n+noff)][k] = src[z][k][n], 64x64 tiles
// via LDS (R8-verified). grid: (z, KD/64, ND/64), 256 thr.
// ---------------------------------------------------------------------------
template<int KD, int ND>
__global__ __launch_bounds__(256)
void transpose_tiled(const void* __restrict__ src, const u16* __restrict__ probe,
                     u16* __restrict__ dst, long dzs, int noff)
{
    const int z  = blockIdx.x;
    const int k0 = blockIdx.y * 64;
    const int n0 = blockIdx.z * 64;
    __shared__ u16 tile[64][66];     // row len 66: <=4-way on column gather
    const int tid = threadIdx.x;
    const bool isbf = (probe[0] == 0x3F80);

    if (isbf) {
        const u16* s = (const u16*)src + (size_t)z * KD * ND + (size_t)k0 * ND + n0;
        #pragma unroll
        for (int p = 0; p < 2; ++p) {
            const int c  = p * 256 + tid;
            const int kk = c >> 3, nn = (c & 7) * 8;
            *(ushort8v*)&tile[kk][nn] = *(const ushort8v*)(s + (size_t)kk * ND + nn);
        }
    } else {
        const float* s = (const float*)src + (size_t)z * KD * ND + (size_t)k0 * ND + n0;
        #pragma unroll
        for (int p = 0; p < 2; ++p) {
            const int c  = p * 256 + tid;
            const int kk = c >> 3, nn = (c & 7) * 8;
            float4 v0 = *(const float4*)(s + (size_t)kk * ND + nn);
            float4 v1 = *(const float4*)(s + (size_t)kk * ND + nn + 4);
            ushort8v t;
            t[0]=f2bf(v0.x); t[1]=f2bf(v0.y); t[2]=f2bf(v0.z); t[3]=f2bf(v0.w);
            t[4]=f2bf(v1.x); t[5]=f2bf(v1.y); t[6]=f2bf(v1.z); t[7]=f2bf(v1.w);
            *(ushort8v*)&tile[kk][nn] = t;
        }
    }
    __syncthreads();

    u16* d = dst + (size_t)z * dzs + (size_t)(n0 + noff) * KD + k0;
    #pragma unroll
    for (int p = 0; p < 2; ++p) {
        const int c  = p * 256 + tid;
        const int nn = c >> 3, kk = (c & 7) * 8;
        ushort8v t;
        #pragma unroll
        for (int j = 0; j < 8; ++j) t[j] = tile[kk + j][nn];
        *(ushort8v*)&d[(size_t)nn * KD + kk] = t;
    }
}

// ---------------------------------------------------------------------------
// Embedding (all f32) + bf16 mirror
// ---------------------------------------------------------------------------
__global__ __launch_bounds__(256)
void embed_kernel(const float* __restrict__ x, const float* __restrict__ emb_w,
                  const float* __restrict__ emb_b, float* __restrict__ h,
                  u16* __restrict__ hb)
{
    const int idx = blockIdx.x * 256 + threadIdx.x;
    const int t = idx >> 8;
    const int d = idx & 255;
    float acc = emb_b[d];
    #pragma unroll
    for (int j = 0; j < DIN; ++j)
        acc += x[t * DIN + j] * emb_w[j * D_ + d];
    h[idx]  = acc;
    hb[idx] = f2bf(acc);
}

// ---------------------------------------------------------------------------
// MFMA GEMM 256x128 tile, 8 waves (R7/R8-verified core: conflicts 0, no
// spills). 2-phase gl_lds double-buffer, one barrier/K-step.
//
// NEW (T1, XCD swizzle): 1-D grid of NX*NY blocks; remap so each XCD's
// round-robin share (bid%8) is a CONTIGUOUS run of (row-panel x all NY
// col-tiles) groups:
//   xcd = bid&7; i = bid>>3; bx = xcd*(NX/8) + i/NY; by = i%NY
// Blocks sharing the A-panel (same bx, all by) then co-reside on ONE XCD's
// L2 instead of being scattered 8 ways -> A re-fetch from L3/HBM drops ~NY x.
// Bijective (NX%8==0 for all uses: 136, 64). Correctness-neutral remap.
//
// MODE 0: dense rows (Mfixed)   MODE 1: gather via atok (MoE w1)
// MODE 2: slot rows (sbase+rr)  (MoE w2)
// EPI 0: bf16 C (QKV)  EPI 1: f32 += & bf16 mirror (o-proj)
// EPI 2: +bias,gelu->bf16 (w1)  EPI 3: +bias->f32 (w2)
// ---------------------------------------------------------------------------
template<int EPI, int MODE, int NT, int NX, int NY>
__global__ __launch_bounds__(512, 4)
void mfma_gemm(const u16* __restrict__ A, int lda,
               const u16* __restrict__ Wt, long wzs, int ldwt,
               const float* __restrict__ biasb, long bzs,
               void* __restrict__ CoutV, int ldc,
               u16* __restrict__ hbout, int Mfixed,
               const int* __restrict__ cnt, const int* __restrict__ base_,
               const int* __restrict__ atok,
               const int* __restrict__ de, const int* __restrict__ dr,
               const int* __restrict__ ndesc)
{
    // XCD-aware bijective remap (T1)
    const int bid = blockIdx.x;
    const int xcd = bid & 7;
    const int ii  = bid >> 3;
    constexpr int PER = NX / 8;
    const int bx = xcd * PER + ii / NY;
    const int by = ii - (ii / NY) * NY;

    int M, r0, sbase = 0, e = 0;
    if constexpr (MODE == 0) {
        M  = Mfixed;
        r0 = bx * 256;
        if (r0 >= M) return;
    } else {
        if (bx >= *ndesc) return;
        e     = de[bx];
        r0    = dr[bx] * 256;
        sbase = base_[e];
        M     = cnt[e];
    }
    const u16*   W    = Wt + (size_t)e * wzs;
    const float* bias = biasb ? (biasb + (size_t)e * bzs) : nullptr;
    const int col0 = by * 128;

    __shared__ __attribute__((aligned(16))) u16 As[2][256 * 32];
    __shared__ __attribute__((aligned(16))) u16 Bs[2][128 * 32];
    __shared__ int stok[256];

    const int tid  = threadIdx.x;
    const int lane = tid & 63;
    const int wave = tid >> 6;            // 0..7
    const int wm = wave & 3, wn = wave >> 2;

    if constexpr (MODE == 1) {
        if (tid < 256) {
            int rr = r0 + tid;
            if (rr >= M) rr = M - 1;
            stok[tid] = atok[sbase + rr];
        }
        __syncthreads();
    }

    // staging geometry (R4-verified swizzle, conflicts == 0)
    const int ss  = (lane & 3) ^ ((lane >> 3) & 3);
    const int rA0 = wave * 16 + (lane >> 2);        // pass-0 row (0..127)
    const int rA1 = rA0 + 128;                      // pass-1 row
    const int rB  = tid >> 2;                       // B col (0..127)
    long ar0, ar1;
    if constexpr (MODE == 1) {
        ar0 = stok[rA0];
        ar1 = stok[rA1];
    } else {
        int rr0 = r0 + rA0; if (rr0 >= M) rr0 = M - 1;
        int rr1 = r0 + rA1; if (rr1 >= M) rr1 = M - 1;
        ar0 = (MODE == 2) ? (long)(sbase + rr0) : (long)rr0;
        ar1 = (MODE == 2) ? (long)(sbase + rr1) : (long)rr1;
    }
    const u16* ga0 = A + ar0 * (long)lda + ss * 8;
    const u16* ga1 = A + ar1 * (long)lda + ss * 8;
    const u16* gw0 = W + (size_t)(col0 + rB) * ldwt + ss * 8;

    floatx4 acc[4][4];
    #pragma unroll
    for (int i = 0; i < 4; ++i)
        #pragma unroll
        for (int j = 0; j < 4; ++j)
            acc[i][j] = (floatx4){0.f, 0.f, 0.f, 0.f};

    const int fm = wm * 64 + (lane & 15);           // A row (0..255)
    const int fn = wn * 64 + (lane & 15);           // B col (0..127)
    const int ps = (lane >> 4) ^ ((lane >> 1) & 3); // reader phys slot

    auto STAGE = [&](int b, int kt) {
        const int ko = kt * 32;
        gl_lds16(ga0 + ko, &As[b][wave * 512 + lane * 8]);
        gl_lds16(ga1 + ko, &As[b][4096 + wave * 512 + lane * 8]);
        gl_lds16(gw0 + ko, &Bs[b][wave * 512 + lane * 8]);
    };

    STAGE(0, 0);
    __syncthreads();

    int buf = 0;
    for (int t = 0; t < NT; ++t) {
        if (t + 1 < NT) STAGE(buf ^ 1, t + 1);

        short8 af[4], bfr[4];
        #pragma unroll
        for (int i = 0; i < 4; ++i)
            af[i]  = *(const short8*)&As[buf][(fm + 16 * i) * 32 + ps * 8];
        #pragma unroll
        for (int j = 0; j < 4; ++j)
            bfr[j] = *(const short8*)&Bs[buf][(fn + 16 * j) * 32 + ps * 8];
        #pragma unroll
        for (int i = 0; i < 4; ++i)
            #pragma unroll
            for (int j = 0; j < 4; ++j)
                acc[i][j] = __builtin_amdgcn_mfma_f32_16x16x32_bf16(
                    af[i], bfr[j], acc[i][j], 0, 0, 0);

        __syncthreads();
        buf ^= 1;
    }

    const int er = wm * 64 + ((lane >> 4) << 2);
    const int ec = wn * 64 + (lane & 15);
    #pragma unroll
    for (int i = 0; i < 4; ++i) {
        #pragma unroll
        for (int reg = 0; reg < 4; ++reg) {
            const int lrow = r0 + er + i * 16 + reg;
            if (lrow >= M) continue;
            const long crow = (MODE == 0) ? (long)lrow : (long)(sbase + lrow);
            #pragma unroll
            for (int j = 0; j < 4; ++j) {
                const int cj = col0 + ec + j * 16;
                const float val = acc[i][j][reg];
                if constexpr (EPI == 0) {
                    ((u16*)CoutV)[crow * ldc + cj] = f2bf(val);
                } else if constexpr (EPI == 1) {
                    const size_t idx = crow * ldc + cj;
                    const float nv = ((float*)CoutV)[idx] + val;
                    ((float*)CoutV)[idx] = nv;
                    hbout[idx] = f2bf(nv);
                } else if constexpr (EPI == 2) {
                    ((u16*)CoutV)[crow * ldc + cj] = f2bf(gelu_f(val + bias[cj]));
                } else {
                    ((float*)CoutV)[crow * ldc + cj] = val + bias[cj];
                }
            }
        }
    }
}

// ---------------------------------------------------------------------------
// MFMA wave attention, one block (256 thr, 4 waves) per (b, head).
// ---------------------------------------------------------------------------
__global__ __launch_bounds__(256)
void attn_kernel(const u16* __restrict__ qkv, u16* __restrict__ o,
                 const float* __restrict__ wfreq, const float* __restrict__ wphase)
{
    const int bh = blockIdx.x;
    const int b  = bh >> 3;
    const int hh = bh & 7;

    __shared__ __attribute__((aligned(16))) u16 Qs[128][40];
    __shared__ __attribute__((aligned(16))) u16 Ks[128][40];
    __shared__ __attribute__((aligned(16))) u16 Vt[32][136];
    __shared__ __attribute__((aligned(16))) u16 Ps[128][136];
    __shared__ float wavec[128];

    const int tid  = threadIdx.x;
    const int lane = tid & 63;
    const int w    = tid >> 6;
    const int col16 = lane & 15;
    const int quad  = lane >> 4;

    const long qbase = (long)b * L_ * 768 + hh * DK_;

    // stage Q, K, V^T (bf16)
    {
        const int row = tid >> 1;
        const int hf  = (tid & 1) * 16;
        const u16* src = qkv + qbase + (long)row * 768 + hf;
        *(ushort8v*)&Qs[row][hf]     = *(const ushort8v*)(src);
        *(ushort8v*)&Qs[row][hf + 8] = *(const ushort8v*)(src + 8);
        *(ushort8v*)&Ks[row][hf]     = *(const ushort8v*)(src + 256);
        *(ushort8v*)&Ks[row][hf + 8] = *(const ushort8v*)(src + 264);
        #pragma unroll
        for (int j = 0; j < 16; ++j)
            Vt[hf + j][row] = src[512 + j];
    }
    if (tid < L_) {
        float f2 = 6.2831853071795864769f * wfreq[hh];
        wavec[tid] = cosf(f2 * (float)tid + wphase[hh]);
    }
    __syncthreads();

    const float scale = 0.17677669529663687f;   // 1/sqrt(32)
    float wv8[8];
    #pragma unroll
    for (int ni = 0; ni < 8; ++ni)
        wv8[ni] = scale * wavec[ni * 16 + col16];

    // S = Q K^T : wave w owns rows [w*32, w*32+32)
    const int m0 = w * 32;
    floatx4 accs[2][8];
    {
        short8 a0 = *(const short8*)&Qs[m0 + col16][quad * 8];
        short8 a1 = *(const short8*)&Qs[m0 + 16 + col16][quad * 8];
        #pragma unroll
        for (int ni = 0; ni < 8; ++ni) {
            short8 bf = *(const short8*)&Ks[ni * 16 + col16][quad * 8];
            accs[0][ni] = __builtin_amdgcn_mfma_f32_16x16x32_bf16(
                a0, bf, (floatx4){0.f,0.f,0.f,0.f}, 0, 0, 0);
            accs[1][ni] = __builtin_amdgcn_mfma_f32_16x16x32_bf16(
                a1, bf, (floatx4){0.f,0.f,0.f,0.f}, 0, 0, 0);
        }
    }
    #pragma unroll
    for (int mi = 0; mi < 2; ++mi)
        #pragma unroll
        for (int ni = 0; ni < 8; ++ni)
            #pragma unroll
            for (int reg = 0; reg < 4; ++reg)
                accs[mi][ni][reg] *= wv8[ni];

    // full-row softmax: row = m0 + mi*16 + quad*4 + reg, in-wave
    #pragma unroll
    for (int mi = 0; mi < 2; ++mi) {
        #pragma unroll
        for (int reg = 0; reg < 4; ++reg) {
            float rmax = -1e30f;
            #pragma unroll
            for (int ni = 0; ni < 8; ++ni)
                rmax = fmaxf(rmax, accs[mi][ni][reg]);
            #pragma unroll
            for (int off = 1; off < 16; off <<= 1)
                rmax = fmaxf(rmax, __shfl_xor(rmax, off));
            float e[8], rsum = 0.0f;
            #pragma unroll
            for (int ni = 0; ni < 8; ++ni) {
                e[ni] = expf(accs[mi][ni][reg] - rmax);
                rsum += e[ni];
            }
            #pragma unroll
            for (int off = 1; off < 16; off <<= 1)
                rsum += __shfl_xor(rsum, off);
            const float inv = 1.0f / rsum;
            const int row = m0 + mi * 16 + quad * 4 + reg;
            #pragma unroll
            for (int ni = 0; ni < 8; ++ni)
                Ps[row][ni * 16 + col16] = f2bf(e[ni] * inv);
        }
    }
    __syncthreads();

    // O = P V
    floatx4 acco[2][2];
    #pragma unroll
    for (int mi = 0; mi < 2; ++mi)
        #pragma unroll
        for (int nj = 0; nj < 2; ++nj)
            acco[mi][nj] = (floatx4){0.f,0.f,0.f,0.f};
    #pragma unroll
    for (int kk = 0; kk < 4; ++kk) {
        short8 a0 = *(const short8*)&Ps[m0 + col16][kk * 32 + quad * 8];
        short8 a1 = *(const short8*)&Ps[m0 + 16 + col16][kk * 32 + quad * 8];
        short8 b0 = *(const short8*)&Vt[col16][kk * 32 + quad * 8];
        short8 b1 = *(const short8*)&Vt[16 + col16][kk * 32 + quad * 8];
        acco[0][0] = __builtin_amdgcn_mfma_f32_16x16x32_bf16(a0, b0, acco[0][0], 0, 0, 0);
        acco[0][1] = __builtin_amdgcn_mfma_f32_16x16x32_bf16(a0, b1, acco[0][1], 0, 0, 0);
        acco[1][0] = __builtin_amdgcn_mfma_f32_16x16x32_bf16(a1, b0, acco[1][0], 0, 0, 0);
        acco[1][1] = __builtin_amdgcn_mfma_f32_16x16x32_bf16(a1, b1, acco[1][1], 0, 0, 0);
    }

    const long obase = (long)b * L_ * D_ + hh * DK_;
    #pragma unroll
    for (int mi = 0; mi < 2; ++mi)
        #pragma unroll
        for (int reg = 0; reg < 4; ++reg) {
            const int row = m0 + mi * 16 + quad * 4 + reg;
            #pragma unroll
            for (int nj = 0; nj < 2; ++nj)
                o[obase + (long)row * D_ + nj * 16 + col16] =
                    f2bf(acco[mi][nj][reg]);
        }
}

// ---------------------------------------------------------------------------
// MoE router: one WAVE per token.
// ---------------------------------------------------------------------------
__global__ __launch_bounds__(256)
void router_kernel(const float* __restrict__ h, const float* __restrict__ rtw,
                   const float* __restrict__ rtb, int* __restrict__ te,
                   float* __restrict__ twt)
{
    const int tid  = threadIdx.x;
    const int lane = tid & 63;
    const int wv   = tid >> 6;
    const int t    = blockIdx.x * 4 + wv;

    const float4 hv = ((const float4*)(h + (long)t * D_))[lane];
    const float4* rp = (const float4*)rtw;

    float lg[NE_];
    #pragma unroll
    for (int e = 0; e < NE_; ++e) lg[e] = 0.0f;
    #pragma unroll
    for (int i = 0; i < 4; ++i) {
        const int d = lane * 4 + i;
        const float xv = (i == 0) ? hv.x : (i == 1) ? hv.y : (i == 2) ? hv.z : hv.w;
        float4 wa = rp[d * 2 + 0];
        float4 wb = rp[d * 2 + 1];
        lg[0] = fmaf(xv, wa.x, lg[0]);
        lg[1] = fmaf(xv, wa.y, lg[1]);
        lg[2] = fmaf(xv, wa.z, lg[2]);
        lg[3] = fmaf(xv, wa.w, lg[3]);
        lg[4] = fmaf(xv, wb.x, lg[4]);
        lg[5] = fmaf(xv, wb.y, lg[5]);
        lg[6] = fmaf(xv, wb.z, lg[6]);
        lg[7] = fmaf(xv, wb.w, lg[7]);
    }
    #pragma unroll
    for (int off = 1; off < 64; off <<= 1)
        #pragma unroll
        for (int e = 0; e < NE_; ++e)
            lg[e] += __shfl_xor(lg[e], off);

    if (lane == 0) {
        #pragma unroll
        for (int e = 0; e < NE_; ++e) lg[e] += rtb[e];
        int i1 = 0; float v1 = lg[0];
        #pragma unroll
        for (int e = 1; e < NE_; ++e) { if (lg[e] > v1) { v1 = lg[e]; i1 = e; } }
        int i2 = (i1 == 0) ? 1 : 0; float v2 = lg[i2];
        #pragma unroll
        for (int e = 0; e < NE_; ++e) {
            if (e != i1 && lg[e] > v2) { v2 = lg[e]; i2 = e; }
        }
        float r   = expf(v2 - v1);
        float wa1 = 1.0f / (1.0f + r);
        te[2 * t]     = i1;
        te[2 * t + 1] = i2;
        twt[2 * t]     = wa1;
        twt[2 * t + 1] = r * wa1;
    }
}

// ---------------------------------------------------------------------------
// Count experts + exclusive scan + zero cursors + tile descriptors (256-row).
// ---------------------------------------------------------------------------
__global__ __launch_bounds__(512)
void countscan_kernel(const int* __restrict__ te, int* __restrict__ cnt,
                      int* __restrict__ base_, int* __restrict__ cursor,
                      int* __restrict__ de, int* __restrict__ dr,
                      int* __restrict__ ndesc)
{
    const int tid = threadIdx.x;
    int c[NE_];
    #pragma unroll
    for (int e = 0; e < NE_; ++e) c[e] = 0;
    for (int i = tid; i < 2 * T_; i += 512) {
        const int e = te[i];
        #pragma unroll
        for (int ee = 0; ee < NE_; ++ee) c[ee] += (e == ee) ? 1 : 0;
    }
    #pragma unroll
    for (int off = 1; off < 64; off <<= 1)
        #pragma unroll
        for (int e = 0; e < NE_; ++e)
            c[e] += __shfl_xor(c[e], off);

    __shared__ int wsum[8][NE_];
    const int lane = tid & 63, wv = tid >> 6;
    if (lane == 0)
        #pragma unroll
        for (int e = 0; e < NE_; ++e) wsum[wv][e] = c[e];
    __syncthreads();
    if (tid == 0) {
        int a = 0, n = 0;
        for (int e = 0; e < NE_; ++e) {
            int s = 0;
            for (int w = 0; w < 8; ++w) s += wsum[w][e];
            cnt[e] = s;
            base_[e] = a;
            a += s;
            const int nb = (s + 255) >> 8;
            for (int rb = 0; rb < nb; ++rb) {
                de[n] = e; dr[n] = rb; ++n;
            }
        }
        *ndesc = n;
    }
    if (tid < NE_) cursor[tid] = 0;
}

// ---------------------------------------------------------------------------
// Scatter with LDS rank aggregation: 8 global atomics per block.
// ---------------------------------------------------------------------------
__global__ __launch_bounds__(256)
void scatter_kernel(const int* __restrict__ te, const int* __restrict__ base_,
                    int* __restrict__ cursor, int* __restrict__ atok,
                    int* __restrict__ tslot)
{
    __shared__ int lcnt[NE_];
    __shared__ int gb[NE_];
    const int tid = threadIdx.x;
    if (tid < NE_) lcnt[tid] = 0;
    __syncthreads();

    const int i0 = blockIdx.x * 512 + tid * 2;
    const int e0 = te[i0], e1 = te[i0 + 1];
    const int r0 = atomicAdd(&lcnt[e0], 1);
    const int r1 = atomicAdd(&lcnt[e1], 1);
    __syncthreads();
    if (tid < NE_) gb[tid] = atomicAdd(&cursor[tid], lcnt[tid]);
    __syncthreads();

    const int s0 = base_[e0] + gb[e0] + r0;
    const int s1 = base_[e1] + gb[e1] + r1;
    atok[s0] = i0 >> 1;
    atok[s1] = i0 >> 1;
    tslot[i0]     = s0;
    tslot[i0 + 1] = s1;
}

// ---------------------------------------------------------------------------
// Combine, vectorized: f32x4 per thread (R8-verified).
// ---------------------------------------------------------------------------
__global__ __launch_bounds__(256)
void combine_kernel(float* __restrict__ h, u16* __restrict__ hb,
                    const float* __restrict__ eo,
                    const float* __restrict__ twt, const int* __restrict__ tslot)
{
    const int i = blockIdx.x * 256 + threadIdx.x;
    const int t = i >> 6;                 // token
    const int g = i & 63;                 // f32x4 group within row (D/4=64)
    const int s0 = tslot[2 * t], s1 = tslot[2 * t + 1];
    const float w0 = twt[2 * t], w1 = twt[2 * t + 1];
    float4 a  = ((const float4*)(eo + (size_t)s0 * D_))[g];
    float4 b  = ((const float4*)(eo + (size_t)s1 * D_))[g];
    float4 hv = ((const float4*)(h + (size_t)t * D_))[g];
    hv.x += w0 * a.x + w1 * b.x;
    hv.y += w0 * a.y + w1 * b.y;
    hv.z += w0 * a.z + w1 * b.z;
    hv.w += w0 * a.w + w1 * b.w;
    ((float4*)(h + (size_t)t * D_))[g] = hv;
    ushort4v pk;
    pk[0] = f2bf(hv.x); pk[1] = f2bf(hv.y); pk[2] = f2bf(hv.z); pk[3] = f2bf(hv.w);
    *(ushort4v*)&hb[(size_t)t * D_ + g * 4] = pk;
}

// ---------------------------------------------------------------------------
// Final: LN on last-position tokens, pred / softplus heads. f32 output.
// ---------------------------------------------------------------------------
__global__ __launch_bounds__(256)
void final_kernel(const float* __restrict__ h, const float* __restrict__ ln_g,
                  const float* __restrict__ ln_b, const float* __restrict__ pred_w,
                  const float* __restrict__ pred_b, const float* __restrict__ unc_w,
                  const float* __restrict__ unc_b, float* __restrict__ out)
{
    const int b = blockIdx.x;
    const int d = threadIdx.x;
    const long t = (long)b * L_ + (L_ - 1);
    const float val = h[t * D_ + d];

    __shared__ float red[4];
    __shared__ float lat[D_];

    float s = val;
    #pragma unroll
    for (int off = 32; off > 0; off >>= 1) s += __shfl_down(s, off);
    if ((d & 63) == 0) red[d >> 6] = s;
    __syncthreads();
    const float mean = (red[0] + red[1] + red[2] + red[3]) * (1.0f / D_);
    __syncthreads();

    const float dv = val - mean;
    s = dv * dv;
    #pragma unroll
    for (int off = 32; off > 0; off >>= 1) s += __shfl_down(s, off);
    if ((d & 63) == 0) red[d >> 6] = s;
    __syncthreads();
    const float var = (red[0] + red[1] + red[2] + red[3]) * (1.0f / D_);

    lat[d] = dv * rsqrtf(var + 1e-5f) * ln_g[d] + ln_b[d];
    __syncthreads();

    if (d < 2 * NOUT_) {
        const int j = d % NOUT_;
        const int sel = d / NOUT_;
        const float* w  = sel ? unc_w : pred_w;
        const float* bb = sel ? unc_b : pred_b;
        float acc = bb[j];
        for (int dd = 0; dd < D_; ++dd)
            acc = fmaf(lat[dd], w[dd * NOUT_ + j], acc);
        if (sel) acc = log1pf(expf(acc));
        out[sel * (B_ * NOUT_) + b * NOUT_ + j] = acc;
    }
}

// ---------------------------------------------------------------------------
extern "C" void kernel_launch(void* const* d_in, const int* in_sizes, int n_in,
                              void* d_out, int out_size, void* d_ws, size_t ws_size,
                              hipStream_t stream)
{
    (void)in_sizes; (void)n_in; (void)out_size; (void)ws_size;

    char* ws = (char*)d_ws;
    size_t off = 0;
    auto alloc = [&](size_t bytes) {
        size_t cur = off;
        off += (bytes + 255) & ~(size_t)255;
        return (void*)(ws + cur);
    };
    float* cs     = (float*)alloc((size_t)NSMALL * 4);
    u16*   qkvt   = (u16*)  alloc((size_t)NL_ * 768 * 256 * 2);
    u16*   wot    = (u16*)  alloc((size_t)NL_ * 256 * 256 * 2);
    u16*   ew1t   = (u16*)  alloc((size_t)3 * NE_ * DFF_ * D_ * 2);
    u16*   ew2t   = (u16*)  alloc((size_t)3 * NE_ * D_ * DFF_ * 2);
    float* h      = (float*)alloc((size_t)T_ * D_ * 4);
    u16*   hb     = (u16*)  alloc((size_t)T_ * D_ * 2);
    // union region: attn-phase {qkvb, ob} aliases moe-phase {hidden, eo}
    char*  uni    = (char*) alloc((size_t)2 * T_ * DFF_ * 2 + (size_t)2 * T_ * D_ * 4);
    u16*   qkvb   = (u16*)  uni;                                    // 25.2 MB
    u16*   ob     = (u16*)  (uni + (size_t)T_ * 768 * 2 + 256);     //  8.4 MB
    u16*   hidden = (u16*)  uni;                                    // 67.1 MB
    float* eo     = (float*)(uni + (size_t)2 * T_ * DFF_ * 2);      // 33.6 MB
    int*   te     = (int*)  alloc((size_t)2 * T_ * 4);
    float* twt    = (float*)alloc((size_t)2 * T_ * 4);
    int*   atok   = (int*)  alloc((size_t)2 * T_ * 4);
    int*   tslot  = (int*)  alloc((size_t)2 * T_ * 4);
    int*   cnt    = (int*)  alloc(64 * 4);
    int*   base_  = (int*)  alloc(64 * 4);
    int*   cursor = (int*)  alloc(64 * 4);
    int*   de     = (int*)  alloc(NDESC_MAX * 4);
    int*   dr     = (int*)  alloc(NDESC_MAX * 4);
    int*   ndesc  = (int*)  alloc(64 * 4);

    SrcPtrs P;
    for (int i = 0; i < 21; ++i) P.p[i] = d_in[i];
    const u16* probe = (const u16*)d_in[15];

    conv_small_kernel<<<(NSMALL + 255) / 256, 256, 0, stream>>>(P, cs);
    transpose_tiled<256,256><<<dim3(NL_, 4, 4), 256, 0, stream>>>(
        d_in[3], probe, qkvt, 768L * 256, 0);
    transpose_tiled<256,256><<<dim3(NL_, 4, 4), 256, 0, stream>>>(
        d_in[4], probe, qkvt, 768L * 256, 256);
    transpose_tiled<256,256><<<dim3(NL_, 4, 4), 256, 0, stream>>>(
        d_in[5], probe, qkvt, 768L * 256, 512);
    transpose_tiled<256,256><<<dim3(NL_, 4, 4), 256, 0, stream>>>(
        d_in[6], probe, wot, 65536L, 0);
    transpose_tiled<256,1024><<<dim3(24, 4, 16), 256, 0, stream>>>(
        d_in[11], probe, ew1t, 262144L, 0);
    transpose_tiled<1024,256><<<dim3(24, 16, 4), 256, 0, stream>>>(
        d_in[13], probe, ew2t, 262144L, 0);

    const float* x      = cs;
    const float* emb_w  = cs + 98304;
    const float* emb_b  = cs + 99840;
    const float* wfreq  = cs + 100096;
    const float* wphase = cs + 100144;
    const float* rtw    = cs + 100192;
    const float* rtb    = cs + 106336;
    const float* eb1    = cs + 106360;
    const float* eb2    = cs + 130936;
    const float* ln_g   = cs + 137080;
    const float* ln_b   = cs + 137336;
    const float* pred_w = cs + 137592;
    const float* pred_b = cs + 138872;
    const float* unc_w  = cs + 138877;
    const float* unc_b  = cs + 140157;

    embed_kernel<<<(T_ * D_) / 256, 256, 0, stream>>>(x, emb_w, emb_b, h, hb);

    for (int i = 0; i < NL_; ++i) {
        // QKV (NX=64 row-panels, NY=6): XCD-grouped so the 6 col-tiles of a
        // row-panel share one XCD's L2 for the A reads.
        mfma_gemm<0, 0, 8, 64, 6><<<64 * 6, 512, 0, stream>>>(
            hb, D_, qkvt + (size_t)i * 768 * 256, 0, 256,
            nullptr, 0, qkvb, 768, nullptr, T_,
            nullptr, nullptr, nullptr, nullptr, nullptr, nullptr);
        attn_kernel<<<B_ * H_, 256, 0, stream>>>(qkvb, ob,
                                                 wfreq + i * H_, wphase + i * H_);
        // o-proj + residual (NX=64, NY=2)
        mfma_gemm<1, 0, 8, 64, 2><<<64 * 2, 512, 0, stream>>>(
            ob, D_, wot + (size_t)i * 65536, 0, 256,
            nullptr, 0, h, D_, hb, T_,
            nullptr, nullptr, nullptr, nullptr, nullptr, nullptr);

        if (i % 2 == 0) {
            const int m = i / 2;
            const u16* w1t = ew1t + (size_t)m * NE_ * DFF_ * D_;
            const u16* w2t = ew2t + (size_t)m * NE_ * D_ * DFF_;
            const float* b1 = eb1 + (size_t)m * NE_ * DFF_;
            const float* b2 = eb2 + (size_t)m * NE_ * D_;
            router_kernel<<<T_ / 4, 256, 0, stream>>>(
                h, rtw + (size_t)m * D_ * NE_, rtb + m * NE_, te, twt);
            countscan_kernel<<<1, 512, 0, stream>>>(te, cnt, base_, cursor,
                                                    de, dr, ndesc);
            scatter_kernel<<<(2 * T_) / 512, 256, 0, stream>>>(te, base_, cursor,
                                                               atok, tslot);
            // w1 (NX=136 descs, NY=8): the 8 DFF-slices of a desc's gathered
            // A-panel (128KB) co-reside on one XCD -> main FETCH saving.
            mfma_gemm<2, 1, 8, NDESC_MAX, 8><<<NDESC_MAX * 8, 512, 0, stream>>>(
                hb, D_, w1t, (long)DFF_ * D_, 256,
                b1, DFF_, hidden, DFF_, nullptr, 0,
                cnt, base_, atok, de, dr, ndesc);
            // w2 (NX=136, NY=2), K=1024
            mfma_gemm<3, 2, 32, NDESC_MAX, 2><<<NDESC_MAX * 2, 512, 0, stream>>>(
                hidden, DFF_, w2t, (long)D_ * DFF_, DFF_,
                b2, D_, eo, D_, nullptr, 0,
                cnt, base_, nullptr, de, dr, ndesc);
            combine_kernel<<<(T_ * 64) / 256, 256, 0, stream>>>(h, hb, eo,
                                                                twt, tslot);
        }
    }

    final_kernel<<<B_, 256, 0, stream>>>(h, ln_g, ln_b, pred_w, pred_b,
                                         unc_w, unc_b, (float*)d_out);
}